// Round 4
// baseline (262.503 us; speedup 1.0000x reference)
//
#include <hip/hip_runtime.h>
#include <hip/hip_bf16.h>

// Liquid NN: h' = -alpha*h + beta*tanh(x_t @ W_fc^T + b_fc + gamma*h)
// B=256 S=64 I=256 H=1024 O=10, t in [0,1], input switches every 1/64.
// Pipeline: split(fp32->bf16 hi/lo) -> MFMA GEMM (K'=768) -> RK4 ODE + out GEMV.

#define NB 256
#define NS 64
#define NI 256
#define NH 1024
#define NO 10
#define NBH (NB * NH)
#define KSUB 2   // RK4 substeps per interval; truncation << fp32 noise floor.

typedef __attribute__((ext_vector_type(8))) short short8;
typedef __attribute__((ext_vector_type(4))) float f32x4;

// ---------------------------------------------------------------------------
// Kernel 0: bf16 hi/lo split. x [b][s][k] -> xhi/xlo [s*NB+b][k] (transposed),
// Wfc [h][k] -> whi/wlo [h][k]. v = hi + lo with |v - hi - lo| ~ 2^-17 |v|.
// ---------------------------------------------------------------------------
__device__ __forceinline__ void split1(float v, unsigned short& h, unsigned short& l)
{
    __hip_bfloat16 bh = __float2bfloat16(v);
    float fh = __bfloat162float(bh);
    __hip_bfloat16 bl = __float2bfloat16(v - fh);   // v - fh exact in fp32
    h = __builtin_bit_cast(unsigned short, bh);
    l = __builtin_bit_cast(unsigned short, bl);
}

__global__ __launch_bounds__(256) void split_kernel(
    const float* __restrict__ x, const float* __restrict__ Wfc,
    __hip_bfloat16* __restrict__ xhi, __hip_bfloat16* __restrict__ xlo,
    __hip_bfloat16* __restrict__ whi, __hip_bfloat16* __restrict__ wlo)
{
    const int bid = blockIdx.x;
    if (bid < 4096) {   // x: 256*64*256 = 4.19M elements, 4 per thread
        const size_t e = ((size_t)bid * 256 + threadIdx.x) * 4;
        const int k  = (int)(e & (NI - 1));
        const int bs = (int)(e >> 8);          // b*NS + s
        const int s  = bs & (NS - 1);
        const int b  = bs >> 6;
        const size_t r = ((size_t)(s * NB + b)) * NI + k;
        float4 v = *(const float4*)(x + e);
        ushort4 h, l;
        split1(v.x, h.x, l.x); split1(v.y, h.y, l.y);
        split1(v.z, h.z, l.z); split1(v.w, h.w, l.w);
        *(ushort4*)((unsigned short*)xhi + r) = h;
        *(ushort4*)((unsigned short*)xlo + r) = l;
    } else {            // Wfc: 1024*256 = 262144 elements
        const size_t e = ((size_t)(bid - 4096) * 256 + threadIdx.x) * 4;
        float4 v = *(const float4*)(Wfc + e);
        ushort4 h, l;
        split1(v.x, h.x, l.x); split1(v.y, h.y, l.y);
        split1(v.z, h.z, l.z); split1(v.w, h.w, l.w);
        *(ushort4*)((unsigned short*)whi + e) = h;
        *(ushort4*)((unsigned short*)wlo + e) = l;
    }
}

// ---------------------------------------------------------------------------
// Kernel 1: U = A @ W^T + b via bf16-split MFMA.
// Logical K' = 768: [A_hi|A_hi|A_lo] x [W_hi|W_lo|W_hi].
// 128x128 tile, BK=32, 4 waves (2x2 of 64x64), mfma_f32_16x16x32_bf16 4x4/wave.
// XCD swizzle: XCD c owns m-panels c*16..c*16+15 (A slice 3MB fits 4MB L2).
// Epilogue: per-wave LDS transpose -> float4 stores (256B/row, full lines).
// ---------------------------------------------------------------------------
#define BM 128
#define BN 128
#define BK 32
#define KT 24    // 768/32

#define GLD16(gp, lp) __builtin_amdgcn_global_load_lds( \
    (const __attribute__((address_space(1))) unsigned int*)(gp), \
    (__attribute__((address_space(3))) unsigned int*)(lp), 16, 0, 0)

__global__ __launch_bounds__(256, 4) void fc_gemm_mfma(
    const __hip_bfloat16* __restrict__ Ahi, const __hip_bfloat16* __restrict__ Alo,
    const __hip_bfloat16* __restrict__ Whi, const __hip_bfloat16* __restrict__ Wlo,
    const float* __restrict__ bfc, float* __restrict__ U)
{
    // 32 KB shared: main loop = lA|lB bf16 double-buffered; epilogue reuses as f32.
    __shared__ float smem_f[8192];
    typedef __hip_bfloat16 (*tile_t)[8][4][16][8];   // [buf][sub][g][row][k8]
    tile_t lA = (tile_t)smem_f;
    tile_t lB = (tile_t)((char*)smem_f + 16384);

    const int t    = threadIdx.x;
    const int w    = t >> 6;
    const int lane = t & 63;
    // XCD-aware mapping: work id wid; m-panel = wid>>3 (consecutive per XCD), n = wid&7
    const int wid  = ((blockIdx.x & 7) << 7) | (blockIdx.x >> 3);
    const int m0   = (wid >> 3) * BM;
    const int n0   = (wid & 7) * BN;
    const int row  = lane & 15;
    const int g    = lane >> 4;

    f32x4 acc[4][4];
#pragma unroll
    for (int i = 0; i < 4; ++i)
#pragma unroll
        for (int j = 0; j < 4; ++j) acc[i][j] = (f32x4){0.f, 0.f, 0.f, 0.f};

    auto stage = [&](int buf, int kt) {
        const __hip_bfloat16* As = (kt < 16) ? Ahi : Alo;
        const __hip_bfloat16* Bs = (kt < 8) ? Whi : ((kt < 16) ? Wlo : Whi);
        const int kp = (kt & 7) * BK;
        const int ms = 2 * w;               // this wave stages subtiles {2w, 2w+1}
        const __hip_bfloat16* ga0 = As + (size_t)(m0 + ms * 16 + row) * NI + kp + g * 8;
        const __hip_bfloat16* gb0 = Bs + (size_t)(n0 + ms * 16 + row) * NI + kp + g * 8;
        GLD16(ga0,            &lA[buf][ms][0][0][0]);
        GLD16(ga0 + 16 * NI,  &lA[buf][ms + 1][0][0][0]);
        GLD16(gb0,            &lB[buf][ms][0][0][0]);
        GLD16(gb0 + 16 * NI,  &lB[buf][ms + 1][0][0][0]);
    };

    const int wm = w >> 1, wn = w & 1;

    auto compute = [&](int buf) {
        short8 af[4], bfr[4];
#pragma unroll
        for (int f = 0; f < 4; ++f)
            af[f] = *(const short8*)((const short*)&lA[buf][wm * 4 + f][0][0][0] + lane * 8);
#pragma unroll
        for (int f = 0; f < 4; ++f)
            bfr[f] = *(const short8*)((const short*)&lB[buf][wn * 4 + f][0][0][0] + lane * 8);
#pragma unroll
        for (int fm = 0; fm < 4; ++fm)
#pragma unroll
            for (int fn = 0; fn < 4; ++fn)
                acc[fm][fn] = __builtin_amdgcn_mfma_f32_16x16x32_bf16(
                    af[fm], bfr[fn], acc[fm][fn], 0, 0, 0);
    };

    stage(0, 0);
    __syncthreads();
#pragma unroll 2
    for (int kt = 0; kt < KT; ++kt) {
        const int cur = kt & 1;
        if (kt + 1 < KT) stage(cur ^ 1, kt + 1);   // prefetch overlaps compute
        compute(cur);
        __syncthreads();                            // drains vmcnt for cur^1
    }

    // --- Coalesced epilogue via per-wave LDS transpose ----------------------
    // frag C/D layout: col=lane&15 (n), row=(lane>>4)*4+reg (m)  [m89-verified]
    // Per fm: wave dumps 16m x 64n f32 to LDS [16][68], reads back 4 rows x
    // 16 lanes x float4 -> 256B contiguous per row.
    __syncthreads();                                // all compute reads done
    float* ep = smem_f + w * 1088;                  // 16*68 floats per wave
    float bias[4];
#pragma unroll
    for (int fn = 0; fn < 4; ++fn)
        bias[fn] = bfc[n0 + wn * 64 + fn * 16 + row];

#pragma unroll
    for (int fm = 0; fm < 4; ++fm) {
#pragma unroll
        for (int fn = 0; fn < 4; ++fn)
#pragma unroll
            for (int r = 0; r < 4; ++r)
                ep[(g * 4 + r) * 68 + fn * 16 + row] = acc[fm][fn][r] + bias[fn];
        __syncthreads();
#pragma unroll
        for (int k = 0; k < 4; ++k) {
            const int rl = 4 * k + g;               // row_local 0..15
            float4 v = *(const float4*)&ep[rl * 68 + row * 4];
            const size_t gm = (size_t)(m0 + wm * 64 + fm * 16 + rl);
            *(float4*)&U[gm * NH + n0 + wn * 64 + row * 4] = v;
        }
        __syncthreads();
    }
}

// ---------------------------------------------------------------------------
// Kernel 2: per-element RK4 + fused output GEMV.  One block per batch b,
// 1024 threads (one per h).  tanh(u+ga*h) = 1 - 2/(1 + exp2(c*h + d)).
// U[snext] prefetched at distance 2 (~900cyc HBM latency > 1 interval of work).
// ---------------------------------------------------------------------------
__device__ __forceinline__ float f_eval(float h, float c, float d, float na, float be)
{
    float z2 = fmaf(c, h, d);
#if __has_builtin(__builtin_amdgcn_exp2f)
    float e = __builtin_amdgcn_exp2f(z2);
#else
    float e = __expf(0.69314718056f * z2);
#endif
    float th = fmaf(-2.0f, __builtin_amdgcn_rcpf(e + 1.0f), 1.0f);
    return fmaf(na, h, be * th);
}

__global__ __launch_bounds__(1024) void ode_out(
    const float* __restrict__ U, const float* __restrict__ alpha,
    const float* __restrict__ beta, const float* __restrict__ gamma,
    const float* __restrict__ Wout, const float* __restrict__ bout,
    float* __restrict__ out)
{
    const int b   = blockIdx.x;
    const int hh  = threadIdx.x;            // 0..1023
    const int idx = b * NH + hh;
    const float na = -alpha[hh];
    const float be = beta[hh];
    const float L2E2 = 2.8853900817779268f;          // 2*log2(e)
    const float c   = L2E2 * gamma[hh];
    const float dt  = 1.0f / (float)(NS * KSUB);
    const float hdt = 0.5f * dt;
    const float dt6 = dt * (1.0f / 6.0f);

    float h = 0.f;
    float u_cur = U[idx];
    float u_nx  = U[NBH + idx];
#pragma unroll 1
    for (int s = 0; s < NS; ++s) {
        const int sp = (s + 2 < NS) ? s + 2 : NS - 1;
        const float u_ft = U[(size_t)sp * NBH + idx];   // distance-2 prefetch
        const float d = L2E2 * u_cur;
#pragma unroll
        for (int k = 0; k < KSUB; ++k) {
            float k1 = f_eval(h, c, d, na, be);
            float k2 = f_eval(fmaf(hdt, k1, h), c, d, na, be);
            float k3 = f_eval(fmaf(hdt, k2, h), c, d, na, be);
            float k4 = f_eval(fmaf(dt, k3, h), c, d, na, be);
            float t1 = k2 + k3;
            float t2 = k1 + k4;
            h = fmaf(dt6, fmaf(2.0f, t1, t2), h);
        }
        u_cur = u_nx;
        u_nx  = u_ft;
    }

    // fused GEMV: out[b][o] = sum_h h * Wout[o][h] + bout[o]
    __shared__ float red[16][NO];
    float part[NO];
#pragma unroll
    for (int o = 0; o < NO; ++o)
        part[o] = h * Wout[(size_t)o * NH + hh];
#pragma unroll
    for (int o = 0; o < NO; ++o)
#pragma unroll
        for (int off = 32; off > 0; off >>= 1)
            part[o] += __shfl_down(part[o], off, 64);

    const int wid2 = hh >> 6, lane = hh & 63;
    if (lane == 0)
#pragma unroll
        for (int o = 0; o < NO; ++o) red[wid2][o] = part[o];
    __syncthreads();
    if (hh < NO) {
        float acc = bout[hh];
#pragma unroll
        for (int ww = 0; ww < 16; ++ww) acc += red[ww][hh];
        out[b * NO + hh] = acc;
    }
}

// ---------------------------------------------------------------------------
extern "C" void kernel_launch(void* const* d_in, const int* in_sizes, int n_in,
                              void* d_out, int out_size, void* d_ws, size_t ws_size,
                              hipStream_t stream)
{
    const float* x     = (const float*)d_in[0];
    const float* Wfc   = (const float*)d_in[1];
    const float* bfc   = (const float*)d_in[2];
    const float* alpha = (const float*)d_in[3];
    const float* beta  = (const float*)d_in[4];
    const float* gamma = (const float*)d_in[5];
    const float* Wout  = (const float*)d_in[6];
    const float* bout  = (const float*)d_in[7];
    float* out = (float*)d_out;

    // workspace: U fp32 64MiB | xhi 8MiB | xlo 8MiB | whi .5MiB | wlo .5MiB
    float* U = (float*)d_ws;
    __hip_bfloat16* xhi = (__hip_bfloat16*)(U + (size_t)NS * NB * NH);
    __hip_bfloat16* xlo = xhi + (size_t)NS * NB * NI;
    __hip_bfloat16* whi = xlo + (size_t)NS * NB * NI;
    __hip_bfloat16* wlo = whi + (size_t)NH * NI;

    split_kernel<<<4096 + 256, 256, 0, stream>>>(x, Wfc, xhi, xlo, whi, wlo);

    fc_gemm_mfma<<<(NH / BN) * ((NS * NB) / BM), 256, 0, stream>>>(
        xhi, xlo, whi, wlo, bfc, U);

    ode_out<<<NB, 1024, 0, stream>>>(U, alpha, beta, gamma, Wout, bout, out);
}

// Round 5
// 213.681 us; speedup vs baseline: 1.2285x; 1.2285x over previous
//
#include <hip/hip_runtime.h>
#include <hip/hip_bf16.h>

// Liquid NN: h' = -alpha*h + beta*tanh(x_t @ W_fc^T + b_fc + gamma*h)
// B=256 S=64 I=256 H=1024 O=10, t in [0,1], input switches every 1/64.
// Pipeline: split(fp32->bf16 hi/lo) -> MFMA GEMM (K'=768) -> RK4 ODE (4 states/thread,
// fused output GEMV via atomics).

#define NB 256
#define NS 64
#define NI 256
#define NH 1024
#define NO 10
#define NBH (NB * NH)
#define KSUB 2   // RK4 substeps per interval; truncation << fp32 noise floor.

typedef __attribute__((ext_vector_type(8))) short short8;
typedef __attribute__((ext_vector_type(4))) float f32x4;

// ---------------------------------------------------------------------------
// Kernel 0: bf16 hi/lo split. x [b][s][k] -> xhi/xlo [s*NB+b][k] (transposed),
// Wfc [h][k] -> whi/wlo [h][k]. v = hi + lo with |v - hi - lo| ~ 2^-17 |v|.
// ---------------------------------------------------------------------------
__device__ __forceinline__ void split1(float v, unsigned short& h, unsigned short& l)
{
    __hip_bfloat16 bh = __float2bfloat16(v);
    float fh = __bfloat162float(bh);
    __hip_bfloat16 bl = __float2bfloat16(v - fh);   // v - fh exact in fp32
    h = __builtin_bit_cast(unsigned short, bh);
    l = __builtin_bit_cast(unsigned short, bl);
}

__global__ __launch_bounds__(256) void split_kernel(
    const float* __restrict__ x, const float* __restrict__ Wfc,
    __hip_bfloat16* __restrict__ xhi, __hip_bfloat16* __restrict__ xlo,
    __hip_bfloat16* __restrict__ whi, __hip_bfloat16* __restrict__ wlo)
{
    const int bid = blockIdx.x;
    if (bid < 4096) {   // x: 256*64*256 = 4.19M elements, 4 per thread
        const size_t e = ((size_t)bid * 256 + threadIdx.x) * 4;
        const int k  = (int)(e & (NI - 1));
        const int bs = (int)(e >> 8);          // b*NS + s
        const int s  = bs & (NS - 1);
        const int b  = bs >> 6;
        const size_t r = ((size_t)(s * NB + b)) * NI + k;
        float4 v = *(const float4*)(x + e);
        ushort4 h, l;
        split1(v.x, h.x, l.x); split1(v.y, h.y, l.y);
        split1(v.z, h.z, l.z); split1(v.w, h.w, l.w);
        *(ushort4*)((unsigned short*)xhi + r) = h;
        *(ushort4*)((unsigned short*)xlo + r) = l;
    } else {            // Wfc: 1024*256 = 262144 elements
        const size_t e = ((size_t)(bid - 4096) * 256 + threadIdx.x) * 4;
        float4 v = *(const float4*)(Wfc + e);
        ushort4 h, l;
        split1(v.x, h.x, l.x); split1(v.y, h.y, l.y);
        split1(v.z, h.z, l.z); split1(v.w, h.w, l.w);
        *(ushort4*)((unsigned short*)whi + e) = h;
        *(ushort4*)((unsigned short*)wlo + e) = l;
    }
}

// ---------------------------------------------------------------------------
// Kernel 1: U = A @ W^T + b via bf16-split MFMA.  (round-3 structure + XCD
// swizzle ONLY — LDS-transpose epilogue and smem union reverted, they were
// the likely round-4 regressor.)
// Logical K' = 768: [A_hi|A_hi|A_lo] x [W_hi|W_lo|W_hi].
// 128x128 tile, BK=32, 4 waves (2x2 of 64x64), mfma_f32_16x16x32_bf16 4x4/wave.
// XCD swizzle: XCD c owns m-panels c*16..c*16+15 (A slice ~2MB fits 4MB L2).
// ---------------------------------------------------------------------------
#define BM 128
#define BN 128
#define BK 32
#define KT 24    // 768/32

#define GLD16(gp, lp) __builtin_amdgcn_global_load_lds( \
    (const __attribute__((address_space(1))) unsigned int*)(gp), \
    (__attribute__((address_space(3))) unsigned int*)(lp), 16, 0, 0)

__global__ __launch_bounds__(256, 4) void fc_gemm_mfma(
    const __hip_bfloat16* __restrict__ Ahi, const __hip_bfloat16* __restrict__ Alo,
    const __hip_bfloat16* __restrict__ Whi, const __hip_bfloat16* __restrict__ Wlo,
    const float* __restrict__ bfc, float* __restrict__ U)
{
    __shared__ __hip_bfloat16 lA[2][8][4][16][8];  // [buf][msub][g][row][k8]
    __shared__ __hip_bfloat16 lB[2][8][4][16][8];  // [buf][nsub][g][row][k8]

    const int t    = threadIdx.x;
    const int w    = t >> 6;
    const int lane = t & 63;
    // XCD-aware mapping: wid = xcd*128 + seq; m-panel = wid>>3, n = wid&7.
    const int wid  = ((blockIdx.x & 7) << 7) | (blockIdx.x >> 3);
    const int m0   = (wid >> 3) * BM;
    const int n0   = (wid & 7) * BN;
    const int row  = lane & 15;
    const int g    = lane >> 4;

    f32x4 acc[4][4];
#pragma unroll
    for (int i = 0; i < 4; ++i)
#pragma unroll
        for (int j = 0; j < 4; ++j) acc[i][j] = (f32x4){0.f, 0.f, 0.f, 0.f};

    auto stage = [&](int buf, int kt) {
        const __hip_bfloat16* As = (kt < 16) ? Ahi : Alo;
        const __hip_bfloat16* Bs = (kt < 8) ? Whi : ((kt < 16) ? Wlo : Whi);
        const int kp = (kt & 7) * BK;
        const int ms = 2 * w;               // this wave stages subtiles {2w, 2w+1}
        const __hip_bfloat16* ga0 = As + (size_t)(m0 + ms * 16 + row) * NI + kp + g * 8;
        const __hip_bfloat16* gb0 = Bs + (size_t)(n0 + ms * 16 + row) * NI + kp + g * 8;
        GLD16(ga0,            &lA[buf][ms][0][0][0]);
        GLD16(ga0 + 16 * NI,  &lA[buf][ms + 1][0][0][0]);
        GLD16(gb0,            &lB[buf][ms][0][0][0]);
        GLD16(gb0 + 16 * NI,  &lB[buf][ms + 1][0][0][0]);
    };

    const int wm = w >> 1, wn = w & 1;

    auto compute = [&](int buf) {
        short8 af[4], bfr[4];
#pragma unroll
        for (int f = 0; f < 4; ++f)
            af[f] = *(const short8*)((const short*)&lA[buf][wm * 4 + f][0][0][0] + lane * 8);
#pragma unroll
        for (int f = 0; f < 4; ++f)
            bfr[f] = *(const short8*)((const short*)&lB[buf][wn * 4 + f][0][0][0] + lane * 8);
#pragma unroll
        for (int fm = 0; fm < 4; ++fm)
#pragma unroll
            for (int fn = 0; fn < 4; ++fn)
                acc[fm][fn] = __builtin_amdgcn_mfma_f32_16x16x32_bf16(
                    af[fm], bfr[fn], acc[fm][fn], 0, 0, 0);
    };

    stage(0, 0);
    __syncthreads();
#pragma unroll 2
    for (int kt = 0; kt < KT; ++kt) {
        const int cur = kt & 1;
        if (kt + 1 < KT) stage(cur ^ 1, kt + 1);   // prefetch overlaps compute
        compute(cur);
        __syncthreads();                            // drains vmcnt for cur^1
    }

    // Epilogue (round-3 form): C/D layout col=lane&15, row=(lane>>4)*4+reg.
#pragma unroll
    for (int fn = 0; fn < 4; ++fn) {
        const int gn = n0 + wn * 64 + fn * 16 + row;
        const float bias = bfc[gn];
#pragma unroll
        for (int fm = 0; fm < 4; ++fm) {
            const int gm = m0 + wm * 64 + fm * 16 + g * 4;
#pragma unroll
            for (int r = 0; r < 4; ++r)
                U[(size_t)(gm + r) * NH + gn] = acc[fm][fn][r] + bias;
        }
    }
}

// ---------------------------------------------------------------------------
// Kernel 2: RK4 integration, 4 states/thread (same h, 4 consecutive b) for
// 4x ILP on the dependent RK chain + latency coverage; distance-2 prefetch.
// Fused output GEMV via block reduction + atomicAdd (out pre-zeroed).
// tanh(u+ga*h) = 1 - 2/(1 + exp2(c*h + d)).
// ---------------------------------------------------------------------------
__device__ __forceinline__ float f_eval(float h, float c, float d, float na, float be)
{
    float z2 = fmaf(c, h, d);
#if __has_builtin(__builtin_amdgcn_exp2f)
    float e = __builtin_amdgcn_exp2f(z2);
#else
    float e = __expf(0.69314718056f * z2);
#endif
    float th = fmaf(-2.0f, __builtin_amdgcn_rcpf(e + 1.0f), 1.0f);
    return fmaf(na, h, be * th);
}

__global__ __launch_bounds__(256) void ode_out(
    const float* __restrict__ U, const float* __restrict__ alpha,
    const float* __restrict__ beta, const float* __restrict__ gamma,
    const float* __restrict__ Wout, const float* __restrict__ bout,
    float* __restrict__ out)
{
    const int k  = blockIdx.x;              // 0..255
    const int t  = threadIdx.x;             // 0..255
    const int b0 = (k >> 2) * 4;            // batch quad
    const int hh = (k & 3) * 256 + t;       // hidden index
    const int base = b0 * NH + hh;          // state j lives at base + j*NH

    const float na = -alpha[hh];
    const float be = beta[hh];
    const float L2E2 = 2.8853900817779268f;          // 2*log2(e)
    const float c   = L2E2 * gamma[hh];
    const float dt  = 1.0f / (float)(NS * KSUB);
    const float hdt = 0.5f * dt;
    const float dt6 = dt * (1.0f / 6.0f);

    float h[4], uc[4], un[4];
#pragma unroll
    for (int j = 0; j < 4; ++j) {
        h[j]  = 0.f;
        uc[j] = U[base + j * NH];
        un[j] = U[NBH + base + j * NH];
    }

#pragma unroll 1
    for (int s = 0; s < NS; ++s) {
        const int sp = (s + 2 < NS) ? s + 2 : NS - 1;
        float uf[4], d[4];
#pragma unroll
        for (int j = 0; j < 4; ++j) {
            uf[j] = U[(size_t)sp * NBH + base + j * NH];  // distance-2 prefetch
            d[j]  = L2E2 * uc[j];
        }
#pragma unroll
        for (int ks = 0; ks < KSUB; ++ks) {
#pragma unroll
            for (int j = 0; j < 4; ++j) {   // 4 independent chains -> ILP
                float k1 = f_eval(h[j], c, d[j], na, be);
                float k2 = f_eval(fmaf(hdt, k1, h[j]), c, d[j], na, be);
                float k3 = f_eval(fmaf(hdt, k2, h[j]), c, d[j], na, be);
                float k4 = f_eval(fmaf(dt, k3, h[j]), c, d[j], na, be);
                float t1 = k2 + k3;
                float t2 = k1 + k4;
                h[j] = fmaf(dt6, fmaf(2.0f, t1, t2), h[j]);
            }
        }
#pragma unroll
        for (int j = 0; j < 4; ++j) { uc[j] = un[j]; un[j] = uf[j]; }
    }

    // Fused GEMV: out[b0+j][o] += sum_hh h[j]*Wout[o][hh]   (out pre-zeroed)
    __shared__ float red[4][4][NO];         // [wave][j][o]
    const int wid2 = t >> 6, lane = t & 63;
#pragma unroll
    for (int j = 0; j < 4; ++j)
#pragma unroll
        for (int o = 0; o < NO; ++o) {
            float p = h[j] * Wout[(size_t)o * NH + hh];
#pragma unroll
            for (int off = 32; off > 0; off >>= 1)
                p += __shfl_down(p, off, 64);
            if (lane == 0) red[wid2][j][o] = p;
        }
    __syncthreads();
    if (t < 40) {
        const int j = t / NO, o = t % NO;
        float sum = red[0][j][o] + red[1][j][o] + red[2][j][o] + red[3][j][o];
        if ((k & 3) == 0) sum += bout[o];   // add bias exactly once per (b,o)
        atomicAdd(&out[(b0 + j) * NO + o], sum);
    }
}

// ---------------------------------------------------------------------------
extern "C" void kernel_launch(void* const* d_in, const int* in_sizes, int n_in,
                              void* d_out, int out_size, void* d_ws, size_t ws_size,
                              hipStream_t stream)
{
    const float* x     = (const float*)d_in[0];
    const float* Wfc   = (const float*)d_in[1];
    const float* bfc   = (const float*)d_in[2];
    const float* alpha = (const float*)d_in[3];
    const float* beta  = (const float*)d_in[4];
    const float* gamma = (const float*)d_in[5];
    const float* Wout  = (const float*)d_in[6];
    const float* bout  = (const float*)d_in[7];
    float* out = (float*)d_out;

    // workspace: U fp32 64MiB | xhi 8MiB | xlo 8MiB | whi .5MiB | wlo .5MiB
    float* U = (float*)d_ws;
    __hip_bfloat16* xhi = (__hip_bfloat16*)(U + (size_t)NS * NB * NH);
    __hip_bfloat16* xlo = xhi + (size_t)NS * NB * NI;
    __hip_bfloat16* whi = xlo + (size_t)NS * NB * NI;
    __hip_bfloat16* wlo = whi + (size_t)NH * NI;

    split_kernel<<<4096 + 256, 256, 0, stream>>>(x, Wfc, xhi, xlo, whi, wlo);

    fc_gemm_mfma<<<(NH / BN) * ((NS * NB) / BM), 256, 0, stream>>>(
        xhi, xlo, whi, wlo, bfc, U);

    hipMemsetAsync(out, 0, (size_t)NB * NO * sizeof(float), stream);
    ode_out<<<NB, 256, 0, stream>>>(U, alpha, beta, gamma, Wout, bout, out);
}

// Round 6
// 210.955 us; speedup vs baseline: 1.2444x; 1.0129x over previous
//
#include <hip/hip_runtime.h>
#include <hip/hip_bf16.h>

// Liquid NN: h' = -alpha*h + beta*tanh(x_t @ W_fc^T + b_fc + gamma*h)
// B=256 S=64 I=256 H=1024 O=10, t in [0,1], input switches every 1/64.
// Pipeline: split(fp32->bf16 hi/lo) -> MFMA GEMM (K'=768, coalesced epilogue)
//           -> RK4 ODE (1 state/thread, 16 waves/CU) + fused output GEMV.

#define NB 256
#define NS 64
#define NI 256
#define NH 1024
#define NO 10
#define NBH (NB * NH)
#define KSUB 2   // RK4 substeps per interval; truncation << fp32 noise floor.

typedef __attribute__((ext_vector_type(8))) short short8;
typedef __attribute__((ext_vector_type(4))) float f32x4;

// ---------------------------------------------------------------------------
// Kernel 0: bf16 hi/lo split. x [b][s][k] -> xhi/xlo [s*NB+b][k] (transposed),
// Wfc [h][k] -> whi/wlo [h][k]. v = hi + lo with |v - hi - lo| ~ 2^-17 |v|.
// ---------------------------------------------------------------------------
__device__ __forceinline__ void split1(float v, unsigned short& h, unsigned short& l)
{
    __hip_bfloat16 bh = __float2bfloat16(v);
    float fh = __bfloat162float(bh);
    __hip_bfloat16 bl = __float2bfloat16(v - fh);   // v - fh exact in fp32
    h = __builtin_bit_cast(unsigned short, bh);
    l = __builtin_bit_cast(unsigned short, bl);
}

__global__ __launch_bounds__(256) void split_kernel(
    const float* __restrict__ x, const float* __restrict__ Wfc,
    __hip_bfloat16* __restrict__ xhi, __hip_bfloat16* __restrict__ xlo,
    __hip_bfloat16* __restrict__ whi, __hip_bfloat16* __restrict__ wlo)
{
    const int bid = blockIdx.x;
    if (bid < 4096) {   // x: 256*64*256 = 4.19M elements, 4 per thread
        const size_t e = ((size_t)bid * 256 + threadIdx.x) * 4;
        const int k  = (int)(e & (NI - 1));
        const int bs = (int)(e >> 8);          // b*NS + s
        const int s  = bs & (NS - 1);
        const int b  = bs >> 6;
        const size_t r = ((size_t)(s * NB + b)) * NI + k;
        float4 v = *(const float4*)(x + e);
        ushort4 h, l;
        split1(v.x, h.x, l.x); split1(v.y, h.y, l.y);
        split1(v.z, h.z, l.z); split1(v.w, h.w, l.w);
        *(ushort4*)((unsigned short*)xhi + r) = h;
        *(ushort4*)((unsigned short*)xlo + r) = l;
    } else {            // Wfc: 1024*256 = 262144 elements
        const size_t e = ((size_t)(bid - 4096) * 256 + threadIdx.x) * 4;
        float4 v = *(const float4*)(Wfc + e);
        ushort4 h, l;
        split1(v.x, h.x, l.x); split1(v.y, h.y, l.y);
        split1(v.z, h.z, l.z); split1(v.w, h.w, l.w);
        *(ushort4*)((unsigned short*)whi + e) = h;
        *(ushort4*)((unsigned short*)wlo + e) = l;
    }
}

// ---------------------------------------------------------------------------
// Kernel 1: U = A @ W^T + b via bf16-split MFMA.
// Logical K' = 768: [A_hi|A_hi|A_lo] x [W_hi|W_lo|W_hi].
// 128x128 tile, BK=32, 4 waves (2x2 of 64x64), mfma_f32_16x16x32_bf16 4x4/wave.
// XCD swizzle: XCD c owns m-panels c*16..c*16+15 (A slice ~2MB fits 4MB L2).
// Epilogue: PER-WAVE LDS transpose (reuses lA/lB, no extra __syncthreads, no
// vmcnt drains) -> global_store_dwordx4, 256B/row = full 128B lines.
// ---------------------------------------------------------------------------
#define BM 128
#define BN 128
#define BK 32
#define KT 24    // 768/32

#define GLD16(gp, lp) __builtin_amdgcn_global_load_lds( \
    (const __attribute__((address_space(1))) unsigned int*)(gp), \
    (__attribute__((address_space(3))) unsigned int*)(lp), 16, 0, 0)

__global__ __launch_bounds__(256, 4) void fc_gemm_mfma(
    const __hip_bfloat16* __restrict__ Ahi, const __hip_bfloat16* __restrict__ Alo,
    const __hip_bfloat16* __restrict__ Whi, const __hip_bfloat16* __restrict__ Wlo,
    const float* __restrict__ bfc, float* __restrict__ U)
{
    __shared__ __hip_bfloat16 lA[2][8][4][16][8];  // [buf][msub][g][row][k8] 16KB
    __shared__ __hip_bfloat16 lB[2][8][4][16][8];  // 16KB

    const int t    = threadIdx.x;
    const int w    = t >> 6;
    const int lane = t & 63;
    // XCD-aware mapping: wid = xcd*128 + seq; m-panel = wid>>3, n = wid&7.
    const int wid  = ((blockIdx.x & 7) << 7) | (blockIdx.x >> 3);
    const int m0   = (wid >> 3) * BM;
    const int n0   = (wid & 7) * BN;
    const int row  = lane & 15;
    const int g    = lane >> 4;

    f32x4 acc[4][4];
#pragma unroll
    for (int i = 0; i < 4; ++i)
#pragma unroll
        for (int j = 0; j < 4; ++j) acc[i][j] = (f32x4){0.f, 0.f, 0.f, 0.f};

    auto stage = [&](int buf, int kt) {
        const __hip_bfloat16* As = (kt < 16) ? Ahi : Alo;
        const __hip_bfloat16* Bs = (kt < 8) ? Whi : ((kt < 16) ? Wlo : Whi);
        const int kp = (kt & 7) * BK;
        const int ms = 2 * w;               // this wave stages subtiles {2w, 2w+1}
        const __hip_bfloat16* ga0 = As + (size_t)(m0 + ms * 16 + row) * NI + kp + g * 8;
        const __hip_bfloat16* gb0 = Bs + (size_t)(n0 + ms * 16 + row) * NI + kp + g * 8;
        GLD16(ga0,            &lA[buf][ms][0][0][0]);
        GLD16(ga0 + 16 * NI,  &lA[buf][ms + 1][0][0][0]);
        GLD16(gb0,            &lB[buf][ms][0][0][0]);
        GLD16(gb0 + 16 * NI,  &lB[buf][ms + 1][0][0][0]);
    };

    const int wm = w >> 1, wn = w & 1;

    auto compute = [&](int buf) {
        short8 af[4], bfr[4];
#pragma unroll
        for (int f = 0; f < 4; ++f)
            af[f] = *(const short8*)((const short*)&lA[buf][wm * 4 + f][0][0][0] + lane * 8);
#pragma unroll
        for (int f = 0; f < 4; ++f)
            bfr[f] = *(const short8*)((const short*)&lB[buf][wn * 4 + f][0][0][0] + lane * 8);
#pragma unroll
        for (int fm = 0; fm < 4; ++fm)
#pragma unroll
            for (int fn = 0; fn < 4; ++fn)
                acc[fm][fn] = __builtin_amdgcn_mfma_f32_16x16x32_bf16(
                    af[fm], bfr[fn], acc[fm][fn], 0, 0, 0);
    };

    stage(0, 0);
    __syncthreads();
#pragma unroll 2
    for (int kt = 0; kt < KT; ++kt) {
        const int cur = kt & 1;
        if (kt + 1 < KT) stage(cur ^ 1, kt + 1);   // prefetch overlaps compute
        compute(cur);
        __syncthreads();                            // drains vmcnt for cur^1
        // final iteration's barrier also guarantees all LDS reads are done
        // before the epilogue repurposes lA/lB.
    }

    // --- Per-wave coalesced epilogue ---------------------------------------
    // frag C/D layout: col(n)=lane&15, row(m)=(lane>>4)*4+reg  [m89-verified]
    // Wave-private 16x68 f32 scratch: waves 0,1 in lA; waves 2,3 in lB.
    float* ep = (w < 2) ? (float*)lA + w * 1088 : (float*)lB + (w - 2) * 1088;
    float bias[4];
#pragma unroll
    for (int fn = 0; fn < 4; ++fn)
        bias[fn] = bfc[n0 + wn * 64 + fn * 16 + row];

#pragma unroll
    for (int fm = 0; fm < 4; ++fm) {
#pragma unroll
        for (int fn = 0; fn < 4; ++fn)
#pragma unroll
            for (int r = 0; r < 4; ++r)
                ep[(g * 4 + r) * 68 + fn * 16 + row] = acc[fm][fn][r] + bias[fn];
        asm volatile("s_waitcnt lgkmcnt(0)" ::: "memory");   // wave-local: writes visible
        __builtin_amdgcn_sched_barrier(0);
#pragma unroll
        for (int k = 0; k < 4; ++k) {
            const int rl = 4 * k + g;               // local row 0..15
            float4 v = *(const float4*)&ep[rl * 68 + row * 4];
            const size_t gm = (size_t)(m0 + wm * 64 + fm * 16 + rl);
            *(float4*)&U[gm * NH + n0 + wn * 64 + row * 4] = v;  // 256B/row, full lines
        }
        asm volatile("s_waitcnt lgkmcnt(0)" ::: "memory");   // reads done before overwrite
        __builtin_amdgcn_sched_barrier(0);
    }
}

// ---------------------------------------------------------------------------
// Kernel 2: RK4 integration, 1 state/thread, 1024 blocks x 256 threads
// (16 waves/CU -> TLP hides trans-pipe + memory latency; r1 measured 98.8%
// VALUBusy in this shape).  Distance-2 prefetch on U.  Fused output GEMV via
// block partials + atomicAdd (out pre-zeroed).
//   tanh form: f = fma(-2be, r, fma(-a,h,be)),  r = 1/(1+exp2(c*h+d)).
// ---------------------------------------------------------------------------
__device__ __forceinline__ float f_eval(float h, float c, float d,
                                        float na, float be, float nbe2)
{
    float z2 = fmaf(c, h, d);
#if __has_builtin(__builtin_amdgcn_exp2f)
    float e = __builtin_amdgcn_exp2f(z2);
#else
    float e = __expf(0.69314718056f * z2);
#endif
    float r = __builtin_amdgcn_rcpf(e + 1.0f);
    return fmaf(nbe2, r, fmaf(na, h, be));
}

__global__ __launch_bounds__(256) void ode_out(
    const float* __restrict__ U, const float* __restrict__ alpha,
    const float* __restrict__ beta, const float* __restrict__ gamma,
    const float* __restrict__ Wout, const float* __restrict__ bout,
    float* __restrict__ out)
{
    const int k  = blockIdx.x;              // 0..1023
    const int t  = threadIdx.x;             // 0..255
    const int b  = k >> 2;
    const int hh = (k & 3) * 256 + t;
    const int idx = b * NH + hh;

    const float na   = -alpha[hh];
    const float be   = beta[hh];
    const float nbe2 = -2.0f * be;
    const float L2E2 = 2.8853900817779268f;          // 2*log2(e)
    const float c   = L2E2 * gamma[hh];
    const float dt  = 1.0f / (float)(NS * KSUB);
    const float hdt = 0.5f * dt;
    const float dt6 = dt * (1.0f / 6.0f);

    float h = 0.f;
    float u_cur = U[idx];
    float u_nx  = U[NBH + idx];
#pragma unroll 1
    for (int s = 0; s < NS; ++s) {
        const int sp = (s + 2 < NS) ? s + 2 : NS - 1;
        const float u_ft = U[(size_t)sp * NBH + idx];   // distance-2 prefetch
        const float d = L2E2 * u_cur;
#pragma unroll
        for (int ks = 0; ks < KSUB; ++ks) {
            float k1 = f_eval(h, c, d, na, be, nbe2);
            float k2 = f_eval(fmaf(hdt, k1, h), c, d, na, be, nbe2);
            float k3 = f_eval(fmaf(hdt, k2, h), c, d, na, be, nbe2);
            float k4 = f_eval(fmaf(dt, k3, h), c, d, na, be, nbe2);
            float t1 = k2 + k3;
            float t2 = k1 + k4;
            h = fmaf(dt6, fmaf(2.0f, t1, t2), h);
        }
        u_cur = u_nx;
        u_nx  = u_ft;
    }

    // Fused GEMV partial: out[b][o] += sum_{hh in chunk} h * Wout[o][hh]
    __shared__ float red[4][NO];
    const int wid2 = t >> 6, lane = t & 63;
#pragma unroll
    for (int o = 0; o < NO; ++o) {
        float p = h * Wout[(size_t)o * NH + hh];
#pragma unroll
        for (int off = 32; off > 0; off >>= 1)
            p += __shfl_down(p, off, 64);
        if (lane == 0) red[wid2][o] = p;
    }
    __syncthreads();
    if (t < NO) {
        float sum = red[0][t] + red[1][t] + red[2][t] + red[3][t];
        if ((k & 3) == 0) sum += bout[t];   // bias exactly once per (b,o)
        atomicAdd(&out[b * NO + t], sum);
    }
}

// ---------------------------------------------------------------------------
extern "C" void kernel_launch(void* const* d_in, const int* in_sizes, int n_in,
                              void* d_out, int out_size, void* d_ws, size_t ws_size,
                              hipStream_t stream)
{
    const float* x     = (const float*)d_in[0];
    const float* Wfc   = (const float*)d_in[1];
    const float* bfc   = (const float*)d_in[2];
    const float* alpha = (const float*)d_in[3];
    const float* beta  = (const float*)d_in[4];
    const float* gamma = (const float*)d_in[5];
    const float* Wout  = (const float*)d_in[6];
    const float* bout  = (const float*)d_in[7];
    float* out = (float*)d_out;

    // workspace: U fp32 64MiB | xhi 8MiB | xlo 8MiB | whi .5MiB | wlo .5MiB
    float* U = (float*)d_ws;
    __hip_bfloat16* xhi = (__hip_bfloat16*)(U + (size_t)NS * NB * NH);
    __hip_bfloat16* xlo = xhi + (size_t)NS * NB * NI;
    __hip_bfloat16* whi = xlo + (size_t)NS * NB * NI;
    __hip_bfloat16* wlo = whi + (size_t)NH * NI;

    split_kernel<<<4096 + 256, 256, 0, stream>>>(x, Wfc, xhi, xlo, whi, wlo);

    fc_gemm_mfma<<<(NH / BN) * ((NS * NB) / BM), 256, 0, stream>>>(
        xhi, xlo, whi, wlo, bfc, U);

    hipMemsetAsync(out, 0, (size_t)NB * NO * sizeof(float), stream);
    ode_out<<<(NB * NH) / 256, 256, 0, stream>>>(U, alpha, beta, gamma, Wout, bout, out);
}

// Round 7
// 184.178 us; speedup vs baseline: 1.4253x; 1.1454x over previous
//
#include <hip/hip_runtime.h>
#include <hip/hip_bf16.h>

// Liquid NN: h' = -alpha*h + beta*tanh(x_t @ W_fc^T + b_fc + gamma*h)
// B=256 S=64 I=256 H=1024 O=10, t in [0,1], input switches every 1/64.
// Pipeline: split(fp32->bf16 hi/lo, PRE-TILED to MFMA staging order)
//           -> MFMA GEMM (K'=768, contiguous 1KB global_load_lds)
//           -> RK4 ODE (2048x128, 32 waves/CU, dist-3 prefetch) + fused GEMV.

#define NB 256
#define NS 64
#define NI 256
#define NH 1024
#define NO 10
#define NBH (NB * NH)
#define KSUB 2   // RK4 substeps per interval; truncation << fp32 noise floor.

typedef __attribute__((ext_vector_type(8))) short short8;
typedef __attribute__((ext_vector_type(4))) float f32x4;

// Tiled operand layout (bf16): for 16-row x 32-k subtiles,
//   flat = (((t16 * 8 + kc) * 4 + g) * 16 + row) * 8 + e
// i.e. each 16x32 subtile is 1024 B ordered [g][row][8e] — exactly the order
// global_load_lds writes LDS (lane l = g*16+row takes bytes l*16..l*16+16).
// A: t16 = (s*256+b)/16 (1024 tiles);  W: t16 = h/16 (64 tiles);  kc = k/32.

// ---------------------------------------------------------------------------
// Kernel 0: bf16 hi/lo split + retile. v = hi + lo, |v-hi-lo| ~ 2^-17 |v|.
// One thread per 8 consecutive output elements (16B hi + 16B lo, coalesced).
// ---------------------------------------------------------------------------
__device__ __forceinline__ void split1(float v, unsigned short& h, unsigned short& l)
{
    __hip_bfloat16 bh = __float2bfloat16(v);
    float fh = __bfloat162float(bh);
    __hip_bfloat16 bl = __float2bfloat16(v - fh);   // v - fh exact in fp32
    h = __builtin_bit_cast(unsigned short, bh);
    l = __builtin_bit_cast(unsigned short, bl);
}

#define XCHUNKS 524288   // 256*64*256/8
#define WCHUNKS 32768    // 1024*256/8

__global__ __launch_bounds__(256) void split_kernel(
    const float* __restrict__ x, const float* __restrict__ Wfc,
    unsigned short* __restrict__ xhi, unsigned short* __restrict__ xlo,
    unsigned short* __restrict__ whi, unsigned short* __restrict__ wlo)
{
    const int tid = blockIdx.x * 256 + threadIdx.x;
    const float* src;
    unsigned short *dh, *dl;
    if (tid < XCHUNKS) {
        int c = tid;
        const int row = c & 15; c >>= 4;
        const int g   = c & 3;  c >>= 2;
        const int kc  = c & 7;  c >>= 3;          // c = t16 = s*16 + b/16
        const int s   = c >> 4;
        const int b   = (c & 15) * 16 + row;
        src = x + ((size_t)b * NS + s) * NI + kc * 32 + g * 8;
        dh  = xhi + (size_t)tid * 8;
        dl  = xlo + (size_t)tid * 8;
    } else {
        int c = tid - XCHUNKS;
        const int row = c & 15; c >>= 4;
        const int g   = c & 3;  c >>= 2;
        const int kc  = c & 7;  c >>= 3;          // c = t16 = h/16
        const int h   = c * 16 + row;
        src = Wfc + (size_t)h * NI + kc * 32 + g * 8;
        dh  = whi + (size_t)(tid - XCHUNKS) * 8;
        dl  = wlo + (size_t)(tid - XCHUNKS) * 8;
    }
    float4 v0 = *(const float4*)src;
    float4 v1 = *(const float4*)(src + 4);
    ushort4 h0, l0, h1, l1;
    split1(v0.x, h0.x, l0.x); split1(v0.y, h0.y, l0.y);
    split1(v0.z, h0.z, l0.z); split1(v0.w, h0.w, l0.w);
    split1(v1.x, h1.x, l1.x); split1(v1.y, h1.y, l1.y);
    split1(v1.z, h1.z, l1.z); split1(v1.w, h1.w, l1.w);
    *(ushort4*)dh = h0; *(ushort4*)(dh + 4) = h1;
    *(ushort4*)dl = l0; *(ushort4*)(dl + 4) = l1;
}

// ---------------------------------------------------------------------------
// Kernel 1: U = A @ W^T + b via bf16-split MFMA on pre-tiled operands.
// Logical K' = 768: [A_hi|A_hi|A_lo] x [W_hi|W_lo|W_hi].
// 128x128 tile, BK=32, 4 waves (2x2 of 64x64), mfma_f32_16x16x32_bf16 4x4/wave.
// Staging: each GLD16 reads 64 lanes x 16B CONTIGUOUS (1KB aligned run).
// XCD swizzle: XCD c owns m-panels c*16..c*16+15 (A slice ~2MB fits 4MB L2).
// Epilogue: per-wave LDS transpose -> float4 stores (256B/row, full lines).
// ---------------------------------------------------------------------------
#define BM 128
#define BN 128
#define BK 32
#define KT 24    // 768/32

#define GLD16(gp, lp) __builtin_amdgcn_global_load_lds( \
    (const __attribute__((address_space(1))) unsigned int*)(gp), \
    (__attribute__((address_space(3))) unsigned int*)(lp), 16, 0, 0)

__global__ __launch_bounds__(256, 4) void fc_gemm_mfma(
    const unsigned short* __restrict__ Ahi, const unsigned short* __restrict__ Alo,
    const unsigned short* __restrict__ Whi, const unsigned short* __restrict__ Wlo,
    const float* __restrict__ bfc, float* __restrict__ U)
{
    __shared__ __hip_bfloat16 lA[2][8][4][16][8];  // [buf][msub][g][row][k8] 16KB
    __shared__ __hip_bfloat16 lB[2][8][4][16][8];  // 16KB

    const int t    = threadIdx.x;
    const int w    = t >> 6;
    const int lane = t & 63;
    // XCD-aware mapping: wid = xcd*128 + seq; m-panel = wid>>3, n = wid&7.
    const int wid  = ((blockIdx.x & 7) << 7) | (blockIdx.x >> 3);
    const int m16b = (wid >> 3) * 8;      // first 16-row A tile of this block
    const int n16b = (wid & 7) * 8;       // first 16-row W tile
    const int m0   = m16b * 16;
    const int n0   = n16b * 16;
    const int row  = lane & 15;
    const int g    = lane >> 4;

    f32x4 acc[4][4];
#pragma unroll
    for (int i = 0; i < 4; ++i)
#pragma unroll
        for (int j = 0; j < 4; ++j) acc[i][j] = (f32x4){0.f, 0.f, 0.f, 0.f};

    auto stage = [&](int buf, int kt) {
        const unsigned short* As = (kt < 16) ? Ahi : Alo;
        const unsigned short* Bs = (kt < 8) ? Whi : ((kt < 16) ? Wlo : Whi);
        const int kc = kt & 7;
        const int ms = 2 * w;               // this wave stages subtiles {2w, 2w+1}
        // contiguous: tile base + lane*8 elements (= lane*16 bytes)
        const unsigned short* ga0 = As + (((size_t)(m16b + ms) * 8 + kc) << 9) + lane * 8;
        const unsigned short* gb0 = Bs + (((size_t)(n16b + ms) * 8 + kc) << 9) + lane * 8;
        GLD16(ga0,        &lA[buf][ms][0][0][0]);
        GLD16(ga0 + 4096, &lA[buf][ms + 1][0][0][0]);   // next tile: +8*512 elems
        GLD16(gb0,        &lB[buf][ms][0][0][0]);
        GLD16(gb0 + 4096, &lB[buf][ms + 1][0][0][0]);
    };

    const int wm = w >> 1, wn = w & 1;

    auto compute = [&](int buf) {
        short8 af[4], bfr[4];
#pragma unroll
        for (int f = 0; f < 4; ++f)
            af[f] = *(const short8*)((const short*)&lA[buf][wm * 4 + f][0][0][0] + lane * 8);
#pragma unroll
        for (int f = 0; f < 4; ++f)
            bfr[f] = *(const short8*)((const short*)&lB[buf][wn * 4 + f][0][0][0] + lane * 8);
#pragma unroll
        for (int fm = 0; fm < 4; ++fm)
#pragma unroll
            for (int fn = 0; fn < 4; ++fn)
                acc[fm][fn] = __builtin_amdgcn_mfma_f32_16x16x32_bf16(
                    af[fm], bfr[fn], acc[fm][fn], 0, 0, 0);
    };

    stage(0, 0);
    __syncthreads();
#pragma unroll 2
    for (int kt = 0; kt < KT; ++kt) {
        const int cur = kt & 1;
        if (kt + 1 < KT) stage(cur ^ 1, kt + 1);   // prefetch overlaps compute
        compute(cur);
        __syncthreads();                            // drains vmcnt for cur^1
        // final iteration's barrier also guarantees all LDS reads are done
        // before the epilogue repurposes lA/lB.
    }

    // --- Per-wave coalesced epilogue ---------------------------------------
    // frag C/D layout: col(n)=lane&15, row(m)=(lane>>4)*4+reg  [m89-verified]
    // Wave-private 16x68 f32 scratch: waves 0,1 in lA; waves 2,3 in lB.
    float* ep = (w < 2) ? (float*)lA + w * 1088 : (float*)lB + (w - 2) * 1088;
    float bias[4];
#pragma unroll
    for (int fn = 0; fn < 4; ++fn)
        bias[fn] = bfc[n0 + wn * 64 + fn * 16 + row];

#pragma unroll
    for (int fm = 0; fm < 4; ++fm) {
#pragma unroll
        for (int fn = 0; fn < 4; ++fn)
#pragma unroll
            for (int r = 0; r < 4; ++r)
                ep[(g * 4 + r) * 68 + fn * 16 + row] = acc[fm][fn][r] + bias[fn];
        asm volatile("s_waitcnt lgkmcnt(0)" ::: "memory");   // wave-local visibility
        __builtin_amdgcn_sched_barrier(0);
#pragma unroll
        for (int k = 0; k < 4; ++k) {
            const int rl = 4 * k + g;               // local row 0..15
            float4 v = *(const float4*)&ep[rl * 68 + row * 4];
            const size_t gm = (size_t)(m0 + wm * 64 + fm * 16 + rl);
            *(float4*)&U[gm * NH + n0 + wn * 64 + row * 4] = v;  // full 128B lines
        }
        asm volatile("s_waitcnt lgkmcnt(0)" ::: "memory");   // reads done pre-overwrite
        __builtin_amdgcn_sched_barrier(0);
    }
}

// ---------------------------------------------------------------------------
// Kernel 2: RK4 integration, 1 state/thread.  2048 blocks x 128 threads ->
// 16 blocks/CU x 2 waves = 32 waves/CU (max TLP).  Distance-3 prefetch on U.
// Fused output GEMV via block partials + atomicAdd (out pre-zeroed).
//   tanh form: f = fma(-2be, r, fma(-a,h,be)),  r = 1/(1+exp2(c*h+d)).
// ---------------------------------------------------------------------------
__device__ __forceinline__ float f_eval(float h, float c, float d,
                                        float na, float be, float nbe2)
{
    float z2 = fmaf(c, h, d);
#if __has_builtin(__builtin_amdgcn_exp2f)
    float e = __builtin_amdgcn_exp2f(z2);
#else
    float e = __expf(0.69314718056f * z2);
#endif
    float r = __builtin_amdgcn_rcpf(e + 1.0f);
    return fmaf(nbe2, r, fmaf(na, h, be));
}

__global__ __launch_bounds__(128) void ode_out(
    const float* __restrict__ U, const float* __restrict__ alpha,
    const float* __restrict__ beta, const float* __restrict__ gamma,
    const float* __restrict__ Wout, const float* __restrict__ bout,
    float* __restrict__ out)
{
    const int k  = blockIdx.x;              // 0..2047
    const int t  = threadIdx.x;             // 0..127
    const int b  = k >> 3;
    const int hh = (k & 7) * 128 + t;
    const int idx = b * NH + hh;

    const float na   = -alpha[hh];
    const float be   = beta[hh];
    const float nbe2 = -2.0f * be;
    const float L2E2 = 2.8853900817779268f;          // 2*log2(e)
    const float c   = L2E2 * gamma[hh];
    const float dt  = 1.0f / (float)(NS * KSUB);
    const float hdt = 0.5f * dt;
    const float dt6 = dt * (1.0f / 6.0f);

    float h  = 0.f;
    float u0 = U[idx];
    float u1 = U[NBH + idx];
    float u2 = U[2 * NBH + idx];
#pragma unroll 1
    for (int s = 0; s < NS; ++s) {
        const int sp = (s + 3 < NS) ? s + 3 : NS - 1;
        const float uf = U[(size_t)sp * NBH + idx];   // distance-3 prefetch
        const float d = L2E2 * u0;
#pragma unroll
        for (int ks = 0; ks < KSUB; ++ks) {
            float k1 = f_eval(h, c, d, na, be, nbe2);
            float k2 = f_eval(fmaf(hdt, k1, h), c, d, na, be, nbe2);
            float k3 = f_eval(fmaf(hdt, k2, h), c, d, na, be, nbe2);
            float k4 = f_eval(fmaf(dt, k3, h), c, d, na, be, nbe2);
            float t1 = k2 + k3;
            float t2 = k1 + k4;
            h = fmaf(dt6, fmaf(2.0f, t1, t2), h);
        }
        u0 = u1; u1 = u2; u2 = uf;
    }

    // Fused GEMV partial: out[b][o] += sum_{hh in chunk} h * Wout[o][hh]
    __shared__ float red[2][NO];
    const int wid2 = t >> 6, lane = t & 63;
#pragma unroll
    for (int o = 0; o < NO; ++o) {
        float p = h * Wout[(size_t)o * NH + hh];
#pragma unroll
        for (int off = 32; off > 0; off >>= 1)
            p += __shfl_down(p, off, 64);
        if (lane == 0) red[wid2][o] = p;
    }
    __syncthreads();
    if (t < NO) {
        float sum = red[0][t] + red[1][t];
        if ((k & 7) == 0) sum += bout[t];   // bias exactly once per (b,o)
        atomicAdd(&out[b * NO + t], sum);
    }
}

// ---------------------------------------------------------------------------
extern "C" void kernel_launch(void* const* d_in, const int* in_sizes, int n_in,
                              void* d_out, int out_size, void* d_ws, size_t ws_size,
                              hipStream_t stream)
{
    const float* x     = (const float*)d_in[0];
    const float* Wfc   = (const float*)d_in[1];
    const float* bfc   = (const float*)d_in[2];
    const float* alpha = (const float*)d_in[3];
    const float* beta  = (const float*)d_in[4];
    const float* gamma = (const float*)d_in[5];
    const float* Wout  = (const float*)d_in[6];
    const float* bout  = (const float*)d_in[7];
    float* out = (float*)d_out;

    // workspace: U fp32 64MiB | xhi 8MiB | xlo 8MiB | whi .5MiB | wlo .5MiB
    float* U = (float*)d_ws;
    unsigned short* xhi = (unsigned short*)(U + (size_t)NS * NB * NH);
    unsigned short* xlo = xhi + (size_t)NS * NB * NI;
    unsigned short* whi = xlo + (size_t)NS * NB * NI;
    unsigned short* wlo = whi + (size_t)NH * NI;

    split_kernel<<<(XCHUNKS + WCHUNKS) / 256, 256, 0, stream>>>(
        x, Wfc, xhi, xlo, whi, wlo);

    fc_gemm_mfma<<<(NH / BN) * ((NS * NB) / BM), 256, 0, stream>>>(
        xhi, xlo, whi, wlo, bfc, U);

    hipMemsetAsync(out, 0, (size_t)NB * NO * sizeof(float), stream);
    ode_out<<<(NB * NH) / 128, 128, 0, stream>>>(U, alpha, beta, gamma, Wout, bout, out);
}

// Round 8
// 182.120 us; speedup vs baseline: 1.4414x; 1.0113x over previous
//
#include <hip/hip_runtime.h>
#include <hip/hip_bf16.h>

// Liquid NN: h' = -alpha*h + beta*tanh(x_t @ W_fc^T + b_fc + gamma*h)
// B=256 S=64 I=256 H=1024 O=10, t in [0,1], input switches every 1/64.
// Pipeline: split(fp32->bf16 hi/lo, PRE-TILED to MFMA staging order, + out init)
//           -> MFMA GEMM (K'=768, 3-buffer counted-vmcnt pipeline)
//           -> RK4 ODE (KSUB=1, 2048x128, dist-4 prefetch) + fused GEMV.

#define NB 256
#define NS 64
#define NI 256
#define NH 1024
#define NO 10
#define NBH (NB * NH)
#define KSUB 1   // RK4 substeps per interval; dt=1/64. Truncation worst-unit ~2e-4
                 // rel (lambda*dt~0.2), amplified <~3e-3 < 7.1e-3 threshold.
                 // (KSUB 8->2 changed absmax by ZERO bits -> floor is GEMM bf16-split.)

typedef __attribute__((ext_vector_type(8))) short short8;
typedef __attribute__((ext_vector_type(4))) float f32x4;

// Tiled operand layout (bf16): for 16-row x 32-k subtiles,
//   flat = (((t16 * 8 + kc) * 4 + g) * 16 + row) * 8 + e
// i.e. each 16x32 subtile is 1024 B ordered [g][row][8e] — exactly the order
// global_load_lds writes LDS (lane l = g*16+row takes bytes l*16..l*16+16).
// A: t16 = (s*256+b)/16 (1024 tiles);  W: t16 = h/16 (64 tiles);  kc = k/32.

// ---------------------------------------------------------------------------
// Kernel 0: bf16 hi/lo split + retile + out-bias init. v = hi + lo.
// ---------------------------------------------------------------------------
__device__ __forceinline__ void split1(float v, unsigned short& h, unsigned short& l)
{
    __hip_bfloat16 bh = __float2bfloat16(v);
    float fh = __bfloat162float(bh);
    __hip_bfloat16 bl = __float2bfloat16(v - fh);   // v - fh exact in fp32
    h = __builtin_bit_cast(unsigned short, bh);
    l = __builtin_bit_cast(unsigned short, bl);
}

#define XCHUNKS 524288   // 256*64*256/8
#define WCHUNKS 32768    // 1024*256/8

__global__ __launch_bounds__(256) void split_kernel(
    const float* __restrict__ x, const float* __restrict__ Wfc,
    unsigned short* __restrict__ xhi, unsigned short* __restrict__ xlo,
    unsigned short* __restrict__ whi, unsigned short* __restrict__ wlo,
    const float* __restrict__ bout, float* __restrict__ out)
{
    const int tid = blockIdx.x * 256 + threadIdx.x;
    const float* src;
    unsigned short *dh, *dl;
    if (tid < XCHUNKS) {
        int c = tid;
        const int row = c & 15; c >>= 4;
        const int g   = c & 3;  c >>= 2;
        const int kc  = c & 7;  c >>= 3;          // c = t16 = s*16 + b/16
        const int s   = c >> 4;
        const int b   = (c & 15) * 16 + row;
        src = x + ((size_t)b * NS + s) * NI + kc * 32 + g * 8;
        dh  = xhi + (size_t)tid * 8;
        dl  = xlo + (size_t)tid * 8;
    } else if (tid < XCHUNKS + WCHUNKS) {
        int c = tid - XCHUNKS;
        const int row = c & 15; c >>= 4;
        const int g   = c & 3;  c >>= 2;
        const int kc  = c & 7;  c >>= 3;          // c = t16 = h/16
        const int h   = c * 16 + row;
        src = Wfc + (size_t)h * NI + kc * 32 + g * 8;
        dh  = whi + (size_t)(tid - XCHUNKS) * 8;
        dl  = wlo + (size_t)(tid - XCHUNKS) * 8;
    } else {
        // out-bias init: replaces the hipMemsetAsync launch.  2560 entries.
        const int c = tid - (XCHUNKS + WCHUNKS);   // grid sized exactly: c < 2560
        out[c] = bout[c - (c / NO) * NO];
        return;
    }
    float4 v0 = *(const float4*)src;
    float4 v1 = *(const float4*)(src + 4);
    ushort4 h0, l0, h1, l1;
    split1(v0.x, h0.x, l0.x); split1(v0.y, h0.y, l0.y);
    split1(v0.z, h0.z, l0.z); split1(v0.w, h0.w, l0.w);
    split1(v1.x, h1.x, l1.x); split1(v1.y, h1.y, l1.y);
    split1(v1.z, h1.z, l1.z); split1(v1.w, h1.w, l1.w);
    *(ushort4*)dh = h0; *(ushort4*)(dh + 4) = h1;
    *(ushort4*)dl = l0; *(ushort4*)(dl + 4) = l1;
}

// ---------------------------------------------------------------------------
// Kernel 1: U = A @ W^T + b via bf16-split MFMA on pre-tiled operands.
// Logical K' = 768: [A_hi|A_hi|A_lo] x [W_hi|W_lo|W_hi].
// 128x128 tile, BK=32, 4 waves (2x2 of 64x64), mfma_f32_16x16x32_bf16 4x4/wave.
// 3-buffer LDS (48KB), prefetch distance 2, counted s_waitcnt vmcnt(4) + raw
// s_barrier — loads stay in flight across barriers (T3/T4, never drain to 0
// in the main loop).  Safety: each wave's stage-kt loads are the OLDEST 4 of
// 8 outstanding at the wait; all ds_reads are consumed by MFMAs (in-order DS
// completion) before each barrier, so distance-3 buffer reuse is race-free.
// ---------------------------------------------------------------------------
#define BM 128
#define BN 128
#define BK 32
#define KT 24    // 768/32

#define GLD16(gp, lp) __builtin_amdgcn_global_load_lds( \
    (const __attribute__((address_space(1))) unsigned int*)(gp), \
    (__attribute__((address_space(3))) unsigned int*)(lp), 16, 0, 0)

__global__ __launch_bounds__(256, 4) void fc_gemm_mfma(
    const unsigned short* __restrict__ Ahi, const unsigned short* __restrict__ Alo,
    const unsigned short* __restrict__ Whi, const unsigned short* __restrict__ Wlo,
    const float* __restrict__ bfc, float* __restrict__ U)
{
    __shared__ __hip_bfloat16 lA[3][8][4][16][8];  // [buf][msub][g][row][k8] 24KB
    __shared__ __hip_bfloat16 lB[3][8][4][16][8];  // 24KB

    const int t    = threadIdx.x;
    const int w    = t >> 6;
    const int lane = t & 63;
    // XCD-aware mapping: wid = xcd*128 + seq; m-panel = wid>>3, n = wid&7.
    const int wid  = ((blockIdx.x & 7) << 7) | (blockIdx.x >> 3);
    const int m16b = (wid >> 3) * 8;      // first 16-row A tile of this block
    const int n16b = (wid & 7) * 8;       // first 16-row W tile
    const int m0   = m16b * 16;
    const int n0   = n16b * 16;
    const int row  = lane & 15;
    const int g    = lane >> 4;

    f32x4 acc[4][4];
#pragma unroll
    for (int i = 0; i < 4; ++i)
#pragma unroll
        for (int j = 0; j < 4; ++j) acc[i][j] = (f32x4){0.f, 0.f, 0.f, 0.f};

    auto stage = [&](int buf, int kt) {
        const unsigned short* As = (kt < 16) ? Ahi : Alo;
        const unsigned short* Bs = (kt < 8) ? Whi : ((kt < 16) ? Wlo : Whi);
        const int kc = kt & 7;
        const int ms = 2 * w;               // this wave stages subtiles {2w, 2w+1}
        const unsigned short* ga0 = As + (((size_t)(m16b + ms) * 8 + kc) << 9) + lane * 8;
        const unsigned short* gb0 = Bs + (((size_t)(n16b + ms) * 8 + kc) << 9) + lane * 8;
        GLD16(ga0,        &lA[buf][ms][0][0][0]);
        GLD16(ga0 + 4096, &lA[buf][ms + 1][0][0][0]);   // next tile: +8*512 elems
        GLD16(gb0,        &lB[buf][ms][0][0][0]);
        GLD16(gb0 + 4096, &lB[buf][ms + 1][0][0][0]);
    };

    const int wm = w >> 1, wn = w & 1;

    auto compute = [&](int buf) {
        short8 af[4], bfr[4];
#pragma unroll
        for (int f = 0; f < 4; ++f)
            af[f] = *(const short8*)((const short*)&lA[buf][wm * 4 + f][0][0][0] + lane * 8);
#pragma unroll
        for (int f = 0; f < 4; ++f)
            bfr[f] = *(const short8*)((const short*)&lB[buf][wn * 4 + f][0][0][0] + lane * 8);
#pragma unroll
        for (int fm = 0; fm < 4; ++fm)
#pragma unroll
            for (int fn = 0; fn < 4; ++fn)
                acc[fm][fn] = __builtin_amdgcn_mfma_f32_16x16x32_bf16(
                    af[fm], bfr[fn], acc[fm][fn], 0, 0, 0);
    };

    stage(0, 0);
    stage(1, 1);                            // 8 GLDs in flight per wave
    int cb = 0;                             // buffer holding tile kt
#pragma unroll 1
    for (int kt = 0; kt < KT - 1; ++kt) {
        // stage(kt) = oldest 4 of 8 outstanding -> done after vmcnt(4)
        asm volatile("s_waitcnt vmcnt(4)" ::: "memory");
        __builtin_amdgcn_s_barrier();
        __builtin_amdgcn_sched_barrier(0);
        if (kt + 2 < KT) {
            int sb = cb + 2; if (sb >= 3) sb -= 3;
            stage(sb, kt + 2);
        }
        compute(cb);
        ++cb; if (cb == 3) cb = 0;
    }
    asm volatile("s_waitcnt vmcnt(0)" ::: "memory");   // tail: drain last stage
    __builtin_amdgcn_s_barrier();
    __builtin_amdgcn_sched_barrier(0);
    compute(cb);
    __syncthreads();                        // all LDS reads done before reuse

    // --- Per-wave coalesced epilogue ---------------------------------------
    // frag C/D layout: col(n)=lane&15, row(m)=(lane>>4)*4+reg  [m89-verified]
    float* ep = (float*)lA + w * 1088;      // 16x68 f32 scratch per wave
    float bias[4];
#pragma unroll
    for (int fn = 0; fn < 4; ++fn)
        bias[fn] = bfc[n0 + wn * 64 + fn * 16 + row];

#pragma unroll
    for (int fm = 0; fm < 4; ++fm) {
#pragma unroll
        for (int fn = 0; fn < 4; ++fn)
#pragma unroll
            for (int r = 0; r < 4; ++r)
                ep[(g * 4 + r) * 68 + fn * 16 + row] = acc[fm][fn][r] + bias[fn];
        asm volatile("s_waitcnt lgkmcnt(0)" ::: "memory");   // wave-local visibility
        __builtin_amdgcn_sched_barrier(0);
#pragma unroll
        for (int k = 0; k < 4; ++k) {
            const int rl = 4 * k + g;               // local row 0..15
            float4 v = *(const float4*)&ep[rl * 68 + row * 4];
            const size_t gm = (size_t)(m0 + wm * 64 + fm * 16 + rl);
            *(float4*)&U[gm * NH + n0 + wn * 64 + row * 4] = v;  // full 128B lines
        }
        asm volatile("s_waitcnt lgkmcnt(0)" ::: "memory");   // reads done pre-overwrite
        __builtin_amdgcn_sched_barrier(0);
    }
}

// ---------------------------------------------------------------------------
// Kernel 2: RK4 integration (KSUB=1), 1 state/thread, 2048 blocks x 128.
// Distance-4 prefetch on U.  Fused output GEMV via block partials + atomicAdd
// (out pre-initialized with bias by split_kernel).
//   tanh form: f = fma(-2be, r, fma(-a,h,be)),  r = 1/(1+exp2(c*h+d)).
// ---------------------------------------------------------------------------
__device__ __forceinline__ float f_eval(float h, float c, float d,
                                        float na, float be, float nbe2)
{
    float z2 = fmaf(c, h, d);
#if __has_builtin(__builtin_amdgcn_exp2f)
    float e = __builtin_amdgcn_exp2f(z2);
#else
    float e = __expf(0.69314718056f * z2);
#endif
    float r = __builtin_amdgcn_rcpf(e + 1.0f);
    return fmaf(nbe2, r, fmaf(na, h, be));
}

__global__ __launch_bounds__(128) void ode_out(
    const float* __restrict__ U, const float* __restrict__ alpha,
    const float* __restrict__ beta, const float* __restrict__ gamma,
    const float* __restrict__ Wout, float* __restrict__ out)
{
    const int k  = blockIdx.x;              // 0..2047
    const int t  = threadIdx.x;             // 0..127
    const int b  = k >> 3;
    const int hh = (k & 7) * 128 + t;
    const int idx = b * NH + hh;

    const float na   = -alpha[hh];
    const float be   = beta[hh];
    const float nbe2 = -2.0f * be;
    const float L2E2 = 2.8853900817779268f;          // 2*log2(e)
    const float c   = L2E2 * gamma[hh];
    const float dt  = 1.0f / (float)(NS * KSUB);
    const float hdt = 0.5f * dt;
    const float dt6 = dt * (1.0f / 6.0f);

    float h  = 0.f;
    float u0 = U[idx];
    float u1 = U[NBH + idx];
    float u2 = U[2 * NBH + idx];
    float u3 = U[3 * NBH + idx];
#pragma unroll 1
    for (int s = 0; s < NS; ++s) {
        const int sp = (s + 4 < NS) ? s + 4 : NS - 1;
        const float uf = U[(size_t)sp * NBH + idx];   // distance-4 prefetch
        const float d = L2E2 * u0;
#pragma unroll
        for (int ks = 0; ks < KSUB; ++ks) {
            float k1 = f_eval(h, c, d, na, be, nbe2);
            float k2 = f_eval(fmaf(hdt, k1, h), c, d, na, be, nbe2);
            float k3 = f_eval(fmaf(hdt, k2, h), c, d, na, be, nbe2);
            float k4 = f_eval(fmaf(dt, k3, h), c, d, na, be, nbe2);
            float t1 = k2 + k3;
            float t2 = k1 + k4;
            h = fmaf(dt6, fmaf(2.0f, t1, t2), h);
        }
        u0 = u1; u1 = u2; u2 = u3; u3 = uf;
    }

    // Fused GEMV partial: out[b][o] += sum_{hh in chunk} h * Wout[o][hh]
    __shared__ float red[2][NO];
    const int wid2 = t >> 6, lane = t & 63;
#pragma unroll
    for (int o = 0; o < NO; ++o) {
        float p = h * Wout[(size_t)o * NH + hh];
#pragma unroll
        for (int off = 32; off > 0; off >>= 1)
            p += __shfl_down(p, off, 64);
        if (lane == 0) red[wid2][o] = p;
    }
    __syncthreads();
    if (t < NO)
        atomicAdd(&out[b * NO + t], red[0][t] + red[1][t]);
}

// ---------------------------------------------------------------------------
extern "C" void kernel_launch(void* const* d_in, const int* in_sizes, int n_in,
                              void* d_out, int out_size, void* d_ws, size_t ws_size,
                              hipStream_t stream)
{
    const float* x     = (const float*)d_in[0];
    const float* Wfc   = (const float*)d_in[1];
    const float* bfc   = (const float*)d_in[2];
    const float* alpha = (const float*)d_in[3];
    const float* beta  = (const float*)d_in[4];
    const float* gamma = (const float*)d_in[5];
    const float* Wout  = (const float*)d_in[6];
    const float* bout  = (const float*)d_in[7];
    float* out = (float*)d_out;

    // workspace: U fp32 64MiB | xhi 8MiB | xlo 8MiB | whi .5MiB | wlo .5MiB
    float* U = (float*)d_ws;
    unsigned short* xhi = (unsigned short*)(U + (size_t)NS * NB * NH);
    unsigned short* xlo = xhi + (size_t)NS * NB * NI;
    unsigned short* whi = xlo + (size_t)NS * NB * NI;
    unsigned short* wlo = whi + (size_t)NH * NI;

    // grid covers splits + 2560 out-init entries exactly: 2186 blocks
    split_kernel<<<(XCHUNKS + WCHUNKS + NB * NO) / 256, 256, 0, stream>>>(
        x, Wfc, xhi, xlo, whi, wlo, bout, out);

    fc_gemm_mfma<<<(NH / BN) * ((NS * NB) / BM), 256, 0, stream>>>(
        xhi, xlo, whi, wlo, bfc, U);

    ode_out<<<(NB * NH) / 128, 128, 0, stream>>>(U, alpha, beta, gamma, Wout, out);
}

// Round 9
// 158.762 us; speedup vs baseline: 1.6534x; 1.1471x over previous
//
#include <hip/hip_runtime.h>
#include <hip/hip_bf16.h>

// Liquid NN: h' = -alpha*h + beta*tanh(x_t @ W_fc^T + b_fc + gamma*h)
// B=256 S=64 I=256 H=1024 O=10, t in [0,1], input switches every 1/64.
// Pipeline: split (coalesced read -> LDS retile -> coalesced write, + out init)
//           -> MFMA GEMM (K'=768, r7 2-buffer structure, 64us known-good)
//           -> RK4 ODE (KSUB=1, 8-deep prefetch ring) + fused GEMV.

#define NB 256
#define NS 64
#define NI 256
#define NH 1024
#define NO 10
#define NBH (NB * NH)
#define KSUB 1   // dt=1/64; truncation ~2e-4 rel worst-unit, amplified < 3e-3
                 // < 7.1e-3 threshold (absmax unchanged from KSUB=8 through 1).

typedef __attribute__((ext_vector_type(8))) short short8;
typedef __attribute__((ext_vector_type(4))) float f32x4;

// Tiled operand layout (bf16): per 16-row x 32-k subtile,
//   flat = tile*4096 + (kc*512 + g*128 + row*8 + e)        [= o]
// Each 16x32 subtile is 1024B ordered [g][row][8e] — exactly the order
// global_load_lds writes LDS (lane l = g*16+row takes bytes l*16..+16).
// A: tile = (s*256+b)/16 (1024 tiles);  W: tile = h/16 (64 tiles).

// ---------------------------------------------------------------------------
// Kernel 0: bf16 hi/lo split + retile + out-bias init.
// Block = one 16x256 tile.  Phase 1: coalesced float4 row reads (1KB/wave)
// -> split -> swizzled LDS write (osw = o ^ (g<<2) ^ (kc<<3), <=4-way).
// Phase 2: swizzled LDS read -> LINEAR global stores (16B/lane, 1KB/wave).
// ---------------------------------------------------------------------------
__device__ __forceinline__ void split1(float v, unsigned short& h, unsigned short& l)
{
    __hip_bfloat16 bh = __float2bfloat16(v);
    float fh = __bfloat162float(bh);
    __hip_bfloat16 bl = __float2bfloat16(v - fh);   // v - fh exact in fp32
    h = __builtin_bit_cast(unsigned short, bh);
    l = __builtin_bit_cast(unsigned short, bl);
}

#define XT 1024   // x tiles (s*16 + b/16)
#define WT 64     // W tiles (h/16)

__global__ __launch_bounds__(256) void split_kernel(
    const float* __restrict__ x, const float* __restrict__ Wfc,
    unsigned short* __restrict__ xhi, unsigned short* __restrict__ xlo,
    unsigned short* __restrict__ whi, unsigned short* __restrict__ wlo,
    const float* __restrict__ bout, float* __restrict__ out)
{
    const int bid = blockIdx.x;
    const int t   = threadIdx.x;
    if (bid >= XT + WT) {                    // out-bias init (replaces memset)
        for (int c = t; c < NB * NO; c += 256) out[c] = bout[c % NO];
        return;
    }
    __shared__ unsigned short lhi[4096];
    __shared__ unsigned short llo[4096];

    const float* srcbase;
    size_t row_stride;                       // floats between tile rows
    unsigned short *dsth, *dstl;
    if (bid < XT) {
        const int s = bid >> 4, bq = bid & 15;
        srcbase    = x + ((size_t)(bq * 16) * NS + s) * NI;
        row_stride = (size_t)NS * NI;        // 16384 floats
        dsth = xhi + (size_t)bid * 4096;
        dstl = xlo + (size_t)bid * 4096;
    } else {
        const int wx = bid - XT;
        srcbase    = Wfc + (size_t)(wx * 16) * NI;
        row_stride = NI;
        dsth = whi + (size_t)wx * 4096;
        dstl = wlo + (size_t)wx * 4096;
    }

#pragma unroll
    for (int i = 0; i < 4; ++i) {
        const int flat = t + i * 256;        // float4 slot 0..1023
        const int row  = flat >> 6;
        const int kq   = flat & 63;          // float4 index within row
        float4 v = *(const float4*)(srcbase + (size_t)row * row_stride + kq * 4);
        ushort4 h4, l4;
        split1(v.x, h4.x, l4.x); split1(v.y, h4.y, l4.y);
        split1(v.z, h4.z, l4.z); split1(v.w, h4.w, l4.w);
        const int kc  = kq >> 3;
        const int g   = (kq >> 1) & 3;
        const int e0  = (kq & 1) * 4;
        const int o   = (kc << 9) | (g << 7) | (row << 3) | e0;
        const int osw = o ^ (g << 2) ^ (kc << 3);   // 8B-aligned (bits 0,1 kept)
        *(ushort4*)&lhi[osw] = h4;
        *(ushort4*)&llo[osw] = l4;
    }
    __syncthreads();
#pragma unroll
    for (int i = 0; i < 2; ++i) {
        const int ob  = i * 2048 + t * 8;    // linear output short index
        const int kc  = ob >> 9;
        const int g   = (ob >> 7) & 3;
        const int sw  = (g << 2) ^ (kc << 3);
        ushort4 a = *(const ushort4*)&lhi[ob ^ sw];
        ushort4 b = *(const ushort4*)&lhi[(ob + 4) ^ sw];
        *(ushort4*)(dsth + ob)     = a;
        *(ushort4*)(dsth + ob + 4) = b;
        ushort4 c4 = *(const ushort4*)&llo[ob ^ sw];
        ushort4 d4 = *(const ushort4*)&llo[(ob + 4) ^ sw];
        *(ushort4*)(dstl + ob)     = c4;
        *(ushort4*)(dstl + ob + 4) = d4;
    }
}

// ---------------------------------------------------------------------------
// Kernel 1: U = A @ W^T + b via bf16-split MFMA on pre-tiled operands.
// EXACT r7 structure (64us measured): 2-buffer, one __syncthreads per K-step,
// contiguous 1KB global_load_lds, XCD swizzle, per-wave LDS-transpose epilogue.
// Logical K' = 768: [A_hi|A_hi|A_lo] x [W_hi|W_lo|W_hi].
// ---------------------------------------------------------------------------
#define BM 128
#define BN 128
#define BK 32
#define KT 24    // 768/32

#define GLD16(gp, lp) __builtin_amdgcn_global_load_lds( \
    (const __attribute__((address_space(1))) unsigned int*)(gp), \
    (__attribute__((address_space(3))) unsigned int*)(lp), 16, 0, 0)

__global__ __launch_bounds__(256, 4) void fc_gemm_mfma(
    const unsigned short* __restrict__ Ahi, const unsigned short* __restrict__ Alo,
    const unsigned short* __restrict__ Whi, const unsigned short* __restrict__ Wlo,
    const float* __restrict__ bfc, float* __restrict__ U)
{
    __shared__ __hip_bfloat16 lA[2][8][4][16][8];  // [buf][msub][g][row][k8] 16KB
    __shared__ __hip_bfloat16 lB[2][8][4][16][8];  // 16KB

    const int t    = threadIdx.x;
    const int w    = t >> 6;
    const int lane = t & 63;
    // XCD-aware mapping: wid = xcd*128 + seq; m-panel = wid>>3, n = wid&7.
    const int wid  = ((blockIdx.x & 7) << 7) | (blockIdx.x >> 3);
    const int m16b = (wid >> 3) * 8;      // first 16-row A tile of this block
    const int n16b = (wid & 7) * 8;       // first 16-row W tile
    const int m0   = m16b * 16;
    const int n0   = n16b * 16;
    const int row  = lane & 15;
    const int g    = lane >> 4;

    f32x4 acc[4][4];
#pragma unroll
    for (int i = 0; i < 4; ++i)
#pragma unroll
        for (int j = 0; j < 4; ++j) acc[i][j] = (f32x4){0.f, 0.f, 0.f, 0.f};

    auto stage = [&](int buf, int kt) {
        const unsigned short* As = (kt < 16) ? Ahi : Alo;
        const unsigned short* Bs = (kt < 8) ? Whi : ((kt < 16) ? Wlo : Whi);
        const int kc = kt & 7;
        const int ms = 2 * w;               // this wave stages subtiles {2w, 2w+1}
        const unsigned short* ga0 = As + (((size_t)(m16b + ms) * 8 + kc) << 9) + lane * 8;
        const unsigned short* gb0 = Bs + (((size_t)(n16b + ms) * 8 + kc) << 9) + lane * 8;
        GLD16(ga0,        &lA[buf][ms][0][0][0]);
        GLD16(ga0 + 4096, &lA[buf][ms + 1][0][0][0]);   // next tile: +8*512 elems
        GLD16(gb0,        &lB[buf][ms][0][0][0]);
        GLD16(gb0 + 4096, &lB[buf][ms + 1][0][0][0]);
    };

    const int wm = w >> 1, wn = w & 1;

    auto compute = [&](int buf) {
        short8 af[4], bfr[4];
#pragma unroll
        for (int f = 0; f < 4; ++f)
            af[f] = *(const short8*)((const short*)&lA[buf][wm * 4 + f][0][0][0] + lane * 8);
#pragma unroll
        for (int f = 0; f < 4; ++f)
            bfr[f] = *(const short8*)((const short*)&lB[buf][wn * 4 + f][0][0][0] + lane * 8);
#pragma unroll
        for (int fm = 0; fm < 4; ++fm)
#pragma unroll
            for (int fn = 0; fn < 4; ++fn)
                acc[fm][fn] = __builtin_amdgcn_mfma_f32_16x16x32_bf16(
                    af[fm], bfr[fn], acc[fm][fn], 0, 0, 0);
    };

    stage(0, 0);
    __syncthreads();
#pragma unroll 2
    for (int kt = 0; kt < KT; ++kt) {
        const int cur = kt & 1;
        if (kt + 1 < KT) stage(cur ^ 1, kt + 1);   // prefetch overlaps compute
        compute(cur);
        __syncthreads();                            // drains vmcnt for cur^1
        // final iteration's barrier also guarantees all LDS reads are done
        // before the epilogue repurposes lA/lB.
    }

    // --- Per-wave coalesced epilogue ---------------------------------------
    // frag C/D layout: col(n)=lane&15, row(m)=(lane>>4)*4+reg  [m89-verified]
    float* ep = (w < 2) ? (float*)lA + w * 1088 : (float*)lB + (w - 2) * 1088;
    float bias[4];
#pragma unroll
    for (int fn = 0; fn < 4; ++fn)
        bias[fn] = bfc[n0 + wn * 64 + fn * 16 + row];

#pragma unroll
    for (int fm = 0; fm < 4; ++fm) {
#pragma unroll
        for (int fn = 0; fn < 4; ++fn)
#pragma unroll
            for (int r = 0; r < 4; ++r)
                ep[(g * 4 + r) * 68 + fn * 16 + row] = acc[fm][fn][r] + bias[fn];
        asm volatile("s_waitcnt lgkmcnt(0)" ::: "memory");   // wave-local visibility
        __builtin_amdgcn_sched_barrier(0);
#pragma unroll
        for (int k = 0; k < 4; ++k) {
            const int rl = 4 * k + g;               // local row 0..15
            float4 v = *(const float4*)&ep[rl * 68 + row * 4];
            const size_t gm = (size_t)(m0 + wm * 64 + fm * 16 + rl);
            *(float4*)&U[gm * NH + n0 + wn * 64 + row * 4] = v;  // full 128B lines
        }
        asm volatile("s_waitcnt lgkmcnt(0)" ::: "memory");   // reads done pre-overwrite
        __builtin_amdgcn_sched_barrier(0);
    }
}

// ---------------------------------------------------------------------------
// Kernel 2: RK4 integration (KSUB=1), 1 state/thread, 2048 blocks x 128.
// 8-deep prefetch ring (fully unrolled inner 8 -> static indices, stays in
// VGPRs): 8 independent U loads in flight per thread -> 64KB/CU in flight,
// far above Little's-law need -> BW-bound.  Fused GEMV via atomicAdd
// (out pre-initialized with bias by split_kernel).
// ---------------------------------------------------------------------------
__device__ __forceinline__ float f_eval(float h, float c, float d,
                                        float na, float be, float nbe2)
{
    float z2 = fmaf(c, h, d);
#if __has_builtin(__builtin_amdgcn_exp2f)
    float e = __builtin_amdgcn_exp2f(z2);
#else
    float e = __expf(0.69314718056f * z2);
#endif
    float r = __builtin_amdgcn_rcpf(e + 1.0f);
    return fmaf(nbe2, r, fmaf(na, h, be));
}

__global__ __launch_bounds__(128) void ode_out(
    const float* __restrict__ U, const float* __restrict__ alpha,
    const float* __restrict__ beta, const float* __restrict__ gamma,
    const float* __restrict__ Wout, float* __restrict__ out)
{
    const int k  = blockIdx.x;              // 0..2047
    const int t  = threadIdx.x;             // 0..127
    const int b  = k >> 3;
    const int hh = (k & 7) * 128 + t;
    const int idx = b * NH + hh;

    const float na   = -alpha[hh];
    const float be   = beta[hh];
    const float nbe2 = -2.0f * be;
    const float L2E2 = 2.8853900817779268f;          // 2*log2(e)
    const float c   = L2E2 * gamma[hh];
    const float dt  = 1.0f / (float)(NS * KSUB);
    const float hdt = 0.5f * dt;
    const float dt6 = dt * (1.0f / 6.0f);

    float h = 0.f;
    float u[8];
#pragma unroll
    for (int j = 0; j < 8; ++j)
        u[j] = U[(size_t)j * NBH + idx];     // 8 independent loads up front

#pragma unroll 1
    for (int sc = 0; sc < 8; ++sc) {
        const int s0 = sc * 8;
#pragma unroll
        for (int j = 0; j < 8; ++j) {        // static j -> u[] stays in VGPRs
            const float d = L2E2 * u[j];
            float k1 = f_eval(h, c, d, na, be, nbe2);
            float k2 = f_eval(fmaf(hdt, k1, h), c, d, na, be, nbe2);
            float k3 = f_eval(fmaf(hdt, k2, h), c, d, na, be, nbe2);
            float k4 = f_eval(fmaf(dt, k3, h), c, d, na, be, nbe2);
            float t1 = k2 + k3;
            float t2 = k1 + k4;
            h = fmaf(dt6, fmaf(2.0f, t1, t2), h);
            const int sp = (s0 + j + 8 < NS) ? s0 + j + 8 : NS - 1;
            u[j] = U[(size_t)sp * NBH + idx];   // refill: 8 iterations ahead
        }
    }

    // Fused GEMV partial: out[b][o] += sum_{hh in chunk} h * Wout[o][hh]
    __shared__ float red[2][NO];
    const int wid2 = t >> 6, lane = t & 63;
#pragma unroll
    for (int o = 0; o < NO; ++o) {
        float p = h * Wout[(size_t)o * NH + hh];
#pragma unroll
        for (int off = 32; off > 0; off >>= 1)
            p += __shfl_down(p, off, 64);
        if (lane == 0) red[wid2][o] = p;
    }
    __syncthreads();
    if (t < NO)
        atomicAdd(&out[b * NO + t], red[0][t] + red[1][t]);
}

// ---------------------------------------------------------------------------
extern "C" void kernel_launch(void* const* d_in, const int* in_sizes, int n_in,
                              void* d_out, int out_size, void* d_ws, size_t ws_size,
                              hipStream_t stream)
{
    const float* x     = (const float*)d_in[0];
    const float* Wfc   = (const float*)d_in[1];
    const float* bfc   = (const float*)d_in[2];
    const float* alpha = (const float*)d_in[3];
    const float* beta  = (const float*)d_in[4];
    const float* gamma = (const float*)d_in[5];
    const float* Wout  = (const float*)d_in[6];
    const float* bout  = (const float*)d_in[7];
    float* out = (float*)d_out;

    // workspace: U fp32 64MiB | xhi 8MiB | xlo 8MiB | whi .5MiB | wlo .5MiB
    float* U = (float*)d_ws;
    unsigned short* xhi = (unsigned short*)(U + (size_t)NS * NB * NH);
    unsigned short* xlo = xhi + (size_t)NS * NB * NI;
    unsigned short* whi = xlo + (size_t)NS * NB * NI;
    unsigned short* wlo = whi + (size_t)NH * NI;

    split_kernel<<<XT + WT + 1, 256, 0, stream>>>(
        x, Wfc, xhi, xlo, whi, wlo, bout, out);

    fc_gemm_mfma<<<(NH / BN) * ((NS * NB) / BM), 256, 0, stream>>>(
        xhi, xlo, whi, wlo, bfc, U);

    ode_out<<<(NB * NH) / 128, 128, 0, stream>>>(U, alpha, beta, gamma, Wout, out);
}

// Round 10
// 136.940 us; speedup vs baseline: 1.9169x; 1.1594x over previous
//
#include <hip/hip_runtime.h>
#include <hip/hip_bf16.h>

// Liquid NN: h' = -alpha*h + beta*tanh(x_t @ W_fc^T + b_fc + gamma*h)
// B=256 S=64 I=256 H=1024 O=10, t in [0,1], input switches every 1/64.
// r10: FUSED GEMM+ODE. split (pre-tile bf16 hi/lo) -> fused_ode: per block
// (16 b x 64 h), loop s: MFMA u-tile (W in regs, x via 6-slot LDS ring with
// counted vmcnt) -> lane-local RK4 -> fused output GEMV.  U never exists.

#define NB 256
#define NS 64
#define NI 256
#define NH 1024
#define NO 10

typedef __attribute__((ext_vector_type(8))) short short8;
typedef __attribute__((ext_vector_type(4))) float f32x4;

// Tiled operand layout (bf16): per 16-row x 256-k tile (4096 shorts = 8KB):
//   tile*4096 + kc*512 + (g*16+row)*8 + e   (kc = k/32, g = k-octet)
// Each kc-subtile (1KB) is in global_load_lds order: lane l = g*16+row takes
// bytes l*16..+16.  x: tile = s*16 + b/16;  W: tile = h/16.

// ---------------------------------------------------------------------------
// Kernel 0: bf16 hi/lo split + retile + out-bias init.  (r9, unchanged)
// ---------------------------------------------------------------------------
__device__ __forceinline__ void split1(float v, unsigned short& h, unsigned short& l)
{
    __hip_bfloat16 bh = __float2bfloat16(v);
    float fh = __bfloat162float(bh);
    __hip_bfloat16 bl = __float2bfloat16(v - fh);   // v - fh exact in fp32
    h = __builtin_bit_cast(unsigned short, bh);
    l = __builtin_bit_cast(unsigned short, bl);
}

#define XT 1024   // x tiles (s*16 + b/16)
#define WT 64     // W tiles (h/16)

__global__ __launch_bounds__(256) void split_kernel(
    const float* __restrict__ x, const float* __restrict__ Wfc,
    unsigned short* __restrict__ xhi, unsigned short* __restrict__ xlo,
    unsigned short* __restrict__ whi, unsigned short* __restrict__ wlo,
    const float* __restrict__ bout, float* __restrict__ out)
{
    const int bid = blockIdx.x;
    const int t   = threadIdx.x;
    if (bid >= XT + WT) {                    // out-bias init (atomic targets)
        for (int c = t; c < NB * NO; c += 256) out[c] = bout[c % NO];
        return;
    }
    __shared__ unsigned short lhi[4096];
    __shared__ unsigned short llo[4096];

    const float* srcbase;
    size_t row_stride;
    unsigned short *dsth, *dstl;
    if (bid < XT) {
        const int s = bid >> 4, bq = bid & 15;
        srcbase    = x + ((size_t)(bq * 16) * NS + s) * NI;
        row_stride = (size_t)NS * NI;
        dsth = xhi + (size_t)bid * 4096;
        dstl = xlo + (size_t)bid * 4096;
    } else {
        const int wx = bid - XT;
        srcbase    = Wfc + (size_t)(wx * 16) * NI;
        row_stride = NI;
        dsth = whi + (size_t)wx * 4096;
        dstl = wlo + (size_t)wx * 4096;
    }

#pragma unroll
    for (int i = 0; i < 4; ++i) {
        const int flat = t + i * 256;
        const int row  = flat >> 6;
        const int kq   = flat & 63;
        float4 v = *(const float4*)(srcbase + (size_t)row * row_stride + kq * 4);
        ushort4 h4, l4;
        split1(v.x, h4.x, l4.x); split1(v.y, h4.y, l4.y);
        split1(v.z, h4.z, l4.z); split1(v.w, h4.w, l4.w);
        const int kc  = kq >> 3;
        const int g   = (kq >> 1) & 3;
        const int e0  = (kq & 1) * 4;
        const int o   = (kc << 9) | (g << 7) | (row << 3) | e0;
        const int osw = o ^ (g << 2) ^ (kc << 3);
        *(ushort4*)&lhi[osw] = h4;
        *(ushort4*)&llo[osw] = l4;
    }
    __syncthreads();
#pragma unroll
    for (int i = 0; i < 2; ++i) {
        const int ob  = i * 2048 + t * 8;
        const int kc  = ob >> 9;
        const int g   = (ob >> 7) & 3;
        const int sw  = (g << 2) ^ (kc << 3);
        ushort4 a = *(const ushort4*)&lhi[ob ^ sw];
        ushort4 b = *(const ushort4*)&lhi[(ob + 4) ^ sw];
        *(ushort4*)(dsth + ob)     = a;
        *(ushort4*)(dsth + ob + 4) = b;
        ushort4 c4 = *(const ushort4*)&llo[ob ^ sw];
        ushort4 d4 = *(const ushort4*)&llo[(ob + 4) ^ sw];
        *(ushort4*)(dstl + ob)     = c4;
        *(ushort4*)(dstl + ob + 4) = d4;
    }
}

// ---------------------------------------------------------------------------
// Kernel 1: FUSED split-GEMM + RK4 ODE + output GEMV.
// Block = 16 b-rows x 64 h-cols, 4 waves (one 16x16 u-tile per wave per s).
// W hi/lo fragments in registers (64 VGPR, Whi reused for phases 0 and 2).
// x-slice ring: 6 slots x 16KB LDS, 4 GLD16/wave/slot, vmcnt(20) steady-state.
// MFMA C/D layout (col=lane&15, row=g*4+reg) => lane-local ODE states.
// XCD map: all 16 h-blocks of a b-slice-pair share one XCD (x L2-resident).
// ---------------------------------------------------------------------------
#define RING 6

#define GLD16(gp, lp) __builtin_amdgcn_global_load_lds( \
    (const __attribute__((address_space(1))) unsigned int*)(gp), \
    (__attribute__((address_space(3))) unsigned int*)(lp), 16, 0, 0)

__device__ __forceinline__ float f_eval(float h, float c, float d,
                                        float na, float be, float nbe2)
{
    float z2 = fmaf(c, h, d);
#if __has_builtin(__builtin_amdgcn_exp2f)
    float e = __builtin_amdgcn_exp2f(z2);
#else
    float e = __expf(0.69314718056f * z2);
#endif
    float r = __builtin_amdgcn_rcpf(e + 1.0f);
    return fmaf(nbe2, r, fmaf(na, h, be));
}

__global__ __launch_bounds__(256, 1) void fused_ode(
    const unsigned short* __restrict__ xhi, const unsigned short* __restrict__ xlo,
    const unsigned short* __restrict__ whi, const unsigned short* __restrict__ wlo,
    const float* __restrict__ bfc, const float* __restrict__ alpha,
    const float* __restrict__ beta, const float* __restrict__ gamma,
    const float* __restrict__ Wout, float* __restrict__ out)
{
    __shared__ unsigned short ring[RING][2][8][512];   // [slot][hi/lo][kc][1KB] 96KB
    __shared__ float red[4][4][4][NO];                 // [wave][g][r][o]

    const int t    = threadIdx.x;
    const int w    = t >> 6;
    const int lane = t & 63;
    const int g    = lane >> 4;
    const int col  = lane & 15;
    const int bid  = blockIdx.x;
    // XCD co-location: xcd = bid&7 owns b-slice-pair; 16 h-blocks per pair.
    const int bq = (bid & 7) * 2 + ((bid >> 3) >> 4);   // b-slice 0..15 (16 rows)
    const int hb = (bid >> 3) & 15;                      // h-block 0..15 (64 cols)
    const int hh = hb * 64 + w * 16 + col;               // this lane's h index

    // --- W fragments in registers (16 h-rows x 768 K' per wave) -------------
    short8 wh[8], wl[8];
    const size_t wbase = (size_t)(hb * 4 + w) * 4096 + lane * 8;
#pragma unroll
    for (int kc = 0; kc < 8; ++kc) {
        wh[kc] = *(const short8*)(whi + wbase + kc * 512);
        wl[kc] = *(const short8*)(wlo + wbase + kc * 512);
    }
    const float bias = bfc[hh];
    const float na   = -alpha[hh];
    const float be   = beta[hh];
    const float nbe2 = -2.0f * be;
    const float L2E2 = 2.8853900817779268f;              // 2*log2(e)
    const float cg   = L2E2 * gamma[hh];
    const float dt   = 1.0f / 64.0f;
    const float hdt  = 0.5f * dt;
    const float dt6  = dt * (1.0f / 6.0f);

    auto stage = [&](int slot, int s) {
        const size_t tb = (size_t)(s * 16 + bq) * 4096 + lane * 8;
#pragma unroll
        for (int q = 0; q < 4; ++q) {                    // 16 GLDs total, 4/wave
            const int id = w * 4 + q, part = id >> 3, kc = id & 7;
            const unsigned short* src = (part ? xlo : xhi) + tb + kc * 512;
            GLD16(src, &ring[slot][part][kc][0]);
        }
    };

    float h4[4] = {0.f, 0.f, 0.f, 0.f};                  // ODE states b=bq*16+g*4+r

#pragma unroll
    for (int s = 0; s < RING; ++s) stage(s, s);          // 24 GLDs/wave in flight

    int slot = 0;
#pragma unroll 1
    for (int s = 0; s < NS; ++s) {
        // slot-s loads are this wave's 4 OLDEST -> done once <=20 outstanding.
        if (s < NS - RING)       asm volatile("s_waitcnt vmcnt(20)" ::: "memory");
        else if (s == NS - RING) asm volatile("s_waitcnt vmcnt(0)"  ::: "memory");
        __builtin_amdgcn_sched_barrier(0);
        __builtin_amdgcn_s_barrier();                    // slot fully written
        __builtin_amdgcn_sched_barrier(0);

        const unsigned short* Ah = &ring[slot][0][0][0];
        const unsigned short* Al = &ring[slot][1][0][0];
        f32x4 ac[4];
        // phases 0+1: a_hi x (Whi, Wlo) — one LDS read feeds two MFMAs.
#pragma unroll
        for (int kc = 0; kc < 8; ++kc) {
            short8 a = *(const short8*)(Ah + kc * 512 + lane * 8);
            f32x4 c0 = (kc < 4) ? (f32x4){0.f, 0.f, 0.f, 0.f} : ac[kc & 3];
            f32x4 tm = __builtin_amdgcn_mfma_f32_16x16x32_bf16(a, wh[kc], c0, 0, 0, 0);
            ac[kc & 3] = __builtin_amdgcn_mfma_f32_16x16x32_bf16(a, wl[kc], tm, 0, 0, 0);
        }
        // phase 2: a_lo x Whi.
#pragma unroll
        for (int kc = 0; kc < 8; ++kc) {
            short8 a = *(const short8*)(Al + kc * 512 + lane * 8);
            ac[kc & 3] = __builtin_amdgcn_mfma_f32_16x16x32_bf16(a, wh[kc], ac[kc & 3], 0, 0, 0);
        }
        f32x4 us = (ac[0] + ac[1]) + (ac[2] + ac[3]);    // u for rows g*4+r

        // lane-local RK4 (4 independent states)
#pragma unroll
        for (int r = 0; r < 4; ++r) {
            const float d = L2E2 * (us[r] + bias);
            float k1 = f_eval(h4[r], cg, d, na, be, nbe2);
            float k2 = f_eval(fmaf(hdt, k1, h4[r]), cg, d, na, be, nbe2);
            float k3 = f_eval(fmaf(hdt, k2, h4[r]), cg, d, na, be, nbe2);
            float k4 = f_eval(fmaf(dt, k3, h4[r]), cg, d, na, be, nbe2);
            h4[r] = fmaf(dt6, fmaf(2.0f, k2 + k3, k1 + k4), h4[r]);
        }

        __builtin_amdgcn_sched_barrier(0);
        __builtin_amdgcn_s_barrier();                    // all waves done w/ slot
        __builtin_amdgcn_sched_barrier(0);
        if (s + RING < NS) stage(slot, s + RING);        // recycle slot
        ++slot; if (slot == RING) slot = 0;
    }

    // --- fused output GEMV: out[b][o] += sum_h h4 * Wout[o][h] --------------
#pragma unroll
    for (int o = 0; o < NO; ++o) {
        const float wv = Wout[(size_t)o * NH + hh];
        float p0 = h4[0] * wv, p1 = h4[1] * wv, p2 = h4[2] * wv, p3 = h4[3] * wv;
#pragma unroll
        for (int m = 1; m < 16; m <<= 1) {               // reduce over 16 cols
            p0 += __shfl_xor(p0, m, 64);
            p1 += __shfl_xor(p1, m, 64);
            p2 += __shfl_xor(p2, m, 64);
            p3 += __shfl_xor(p3, m, 64);
        }
        if (col == 0) {
            red[w][g][0][o] = p0; red[w][g][1][o] = p1;
            red[w][g][2][o] = p2; red[w][g][3][o] = p3;
        }
    }
    __syncthreads();
    if (t < 160) {                                       // 16 b-rows x 10 o
        const int o  = t % NO, gr = t / NO;              // gr = g*4+r
        const float sum = red[0][gr >> 2][gr & 3][o] + red[1][gr >> 2][gr & 3][o]
                        + red[2][gr >> 2][gr & 3][o] + red[3][gr >> 2][gr & 3][o];
        atomicAdd(&out[(bq * 16 + gr) * NO + o], sum);
    }
}

// ---------------------------------------------------------------------------
extern "C" void kernel_launch(void* const* d_in, const int* in_sizes, int n_in,
                              void* d_out, int out_size, void* d_ws, size_t ws_size,
                              hipStream_t stream)
{
    const float* x     = (const float*)d_in[0];
    const float* Wfc   = (const float*)d_in[1];
    const float* bfc   = (const float*)d_in[2];
    const float* alpha = (const float*)d_in[3];
    const float* beta  = (const float*)d_in[4];
    const float* gamma = (const float*)d_in[5];
    const float* Wout  = (const float*)d_in[6];
    const float* bout  = (const float*)d_in[7];
    float* out = (float*)d_out;

    // workspace: xhi 8MiB | xlo 8MiB | whi .5MiB | wlo .5MiB  (U eliminated)
    unsigned short* xhi = (unsigned short*)d_ws;
    unsigned short* xlo = xhi + (size_t)NS * NB * NI;
    unsigned short* whi = xlo + (size_t)NS * NB * NI;
    unsigned short* wlo = whi + (size_t)NH * NI;

    split_kernel<<<XT + WT + 1, 256, 0, stream>>>(
        x, Wfc, xhi, xlo, whi, wlo, bout, out);

    fused_ode<<<NB, 256, 0, stream>>>(
        xhi, xlo, whi, wlo, bfc, alpha, beta, gamma, Wout, out);
}